// Round 7
// baseline (315.269 us; speedup 1.0000x reference)
//
#include <hip/hip_runtime.h>
#include <hip/hip_bf16.h>
#include <math.h>

#define Bq 4
#define Lq 2048
#define Dq 512
#define Hq 8
#define DKq 64
#define Uq 24
#define TSCAN 16
#define NTILE (Lq / TSCAN)   // 128
#define JCH 256              // softmax j-chunk
#define NCH (Lq / JCH)       // 8
#define TKCH 8               // top-k chunks per bh

typedef unsigned short ushort_t;
typedef unsigned long long u64;
typedef __attribute__((ext_vector_type(8))) short bfrag8;   // 8 bf16 (4 VGPRs)
typedef __attribute__((ext_vector_type(4))) float facc4;    // MFMA accumulator

__device__ inline ushort_t bf16_rne(float f) {
  unsigned u = __float_as_uint(f);
  u += 0x7FFF + ((u >> 16) & 1);
  return (ushort_t)(u >> 16);
}
__device__ inline float bf16f(ushort_t h) {
  return __uint_as_float(((unsigned)h) << 16);
}
// monotone float -> uint map (no NaNs in inputs)
__device__ inline unsigned fkey(float f) {
  unsigned u = __float_as_uint(f);
  return (u & 0x80000000u) ? ~u : (u | 0x80000000u);
}

// ---------------------------------------------------------------------------
// All 4 weights: fp32 [k][n] -> transposed bf16 hi/lo [n][k] (one launch)
// ---------------------------------------------------------------------------
__global__ __launch_bounds__(256) void transpose_cast4(
    const float* __restrict__ W0, const float* __restrict__ W1,
    const float* __restrict__ W2, const float* __restrict__ W3,
    ushort_t* __restrict__ T0h, ushort_t* __restrict__ T0l,
    ushort_t* __restrict__ T1h, ushort_t* __restrict__ T1l,
    ushort_t* __restrict__ T2h, ushort_t* __restrict__ T3h) {
  __shared__ float tile[32][33];
  int z = blockIdx.z;
  const float* W = z == 0 ? W0 : (z == 1 ? W1 : (z == 2 ? W2 : W3));
  ushort_t* Th = z == 0 ? T0h : (z == 1 ? T1h : (z == 2 ? T2h : T3h));
  ushort_t* Tl = z == 0 ? T0l : (z == 1 ? T1l : nullptr);
  int k0 = blockIdx.x * 32, n0 = blockIdx.y * 32;
  int tx = threadIdx.x & 31, ty = threadIdx.x >> 5;  // ty 0..7
  for (int r = ty; r < 32; r += 8)
    tile[tx][r] = W[(size_t)(k0 + r) * 512 + n0 + tx];
  __syncthreads();
  for (int r = ty; r < 32; r += 8) {
    float v = tile[r][tx];
    ushort_t h = bf16_rne(v);
    Th[(size_t)(n0 + r) * 512 + k0 + tx] = h;
    if (Tl) Tl[(size_t)(n0 + r) * 512 + k0 + tx] = bf16_rne(v - bf16f(h));
  }
}

// ---------------------------------------------------------------------------
// Fused Q/K/V projection GEMM. z=0: Q (split-bf16), z=1: K (split),
// z=2: V (plain hi). A is fp32; hi/lo decompose happens in staging
// (bit-identical to the old cast_hilo + gemm_split path).
// ---------------------------------------------------------------------------
__global__ __launch_bounds__(256) void gemm_qkv(
    const float* __restrict__ Xq, const float* __restrict__ Xk,
    const float* __restrict__ Xv,
    const ushort_t* __restrict__ Wqh, const ushort_t* __restrict__ Wql,
    const ushort_t* __restrict__ Wkh, const ushort_t* __restrict__ Wkl,
    const ushort_t* __restrict__ Wvh,
    const float* __restrict__ bq, const float* __restrict__ bk,
    const float* __restrict__ bv,
    float* __restrict__ qo, float* __restrict__ ko, float* __restrict__ vo) {
  __shared__ ushort_t Ash[128][32], Asl[128][32];  // 16 KB
  __shared__ ushort_t Bsh[64][32], Bsl[64][32];    // 8 KB
  int which = blockIdx.z;
  const float* A = which == 0 ? Xq : (which == 1 ? Xk : Xv);
  const ushort_t* Bh = which == 0 ? Wqh : (which == 1 ? Wkh : Wvh);
  const ushort_t* Bl = which == 0 ? Wql : Wkl;  // unused when which==2
  const float* bias = which == 0 ? bq : (which == 1 ? bk : bv);
  float* C = which == 0 ? qo : (which == 1 ? ko : vo);
  const bool split = which < 2;

  int bm = blockIdx.x, bn = blockIdx.y;
  int tid = threadIdx.x;
  int wave = tid >> 6, lane = tid & 63;
  int wm = (wave & 1) * 64, wn = (wave >> 1) * 32;
  int quad = lane >> 4, lm = lane & 15;
  facc4 acc[4][2] = {};

  for (int k0 = 0; k0 < 512; k0 += 32) {
#pragma unroll
    for (int p = 0; p < 2; ++p) {
      int s = p * 256 + tid;
      int row = s >> 2, kq = (s & 3) * 8;
      const float* src = &A[(size_t)(bm * 128 + row) * 512 + k0 + kq];
      float4 x0 = *(const float4*)src;
      float4 x1 = *(const float4*)(src + 4);
      float xs[8] = {x0.x, x0.y, x0.z, x0.w, x1.x, x1.y, x1.z, x1.w};
      ushort_t hh[8];
#pragma unroll
      for (int e = 0; e < 8; ++e) hh[e] = bf16_rne(xs[e]);
      *(ushort4*)&Ash[row][kq] = *(ushort4*)&hh[0];
      *(ushort4*)&Ash[row][kq + 4] = *(ushort4*)&hh[4];
      if (split) {
        ushort_t ll[8];
#pragma unroll
        for (int e = 0; e < 8; ++e) ll[e] = bf16_rne(xs[e] - bf16f(hh[e]));
        *(ushort4*)&Asl[row][kq] = *(ushort4*)&ll[0];
        *(ushort4*)&Asl[row][kq + 4] = *(ushort4*)&ll[4];
      }
    }
    {
      int row = tid >> 2, kq = (tid & 3) * 8;
      size_t g = (size_t)(bn * 64 + row) * 512 + k0 + kq;
      *(bfrag8*)&Bsh[row][kq] = *(const bfrag8*)&Bh[g];
      if (split) *(bfrag8*)&Bsl[row][kq] = *(const bfrag8*)&Bl[g];
    }
    __syncthreads();
    bfrag8 afh[4], afl[4], bfh[2], bfl[2];
#pragma unroll
    for (int mt = 0; mt < 4; ++mt) {
      afh[mt] = *(bfrag8*)&Ash[wm + mt * 16 + lm][quad * 8];
      if (split) afl[mt] = *(bfrag8*)&Asl[wm + mt * 16 + lm][quad * 8];
    }
#pragma unroll
    for (int nt = 0; nt < 2; ++nt) {
      bfh[nt] = *(bfrag8*)&Bsh[wn + nt * 16 + lm][quad * 8];
      if (split) bfl[nt] = *(bfrag8*)&Bsl[wn + nt * 16 + lm][quad * 8];
    }
#pragma unroll
    for (int mt = 0; mt < 4; ++mt)
#pragma unroll
      for (int nt = 0; nt < 2; ++nt) {
        facc4 a = acc[mt][nt];
        a = __builtin_amdgcn_mfma_f32_16x16x32_bf16(afh[mt], bfh[nt], a, 0, 0, 0);
        if (split) {
          a = __builtin_amdgcn_mfma_f32_16x16x32_bf16(afl[mt], bfh[nt], a, 0, 0, 0);
          a = __builtin_amdgcn_mfma_f32_16x16x32_bf16(afh[mt], bfl[nt], a, 0, 0, 0);
        }
        acc[mt][nt] = a;
      }
    __syncthreads();
  }
#pragma unroll
  for (int mt = 0; mt < 4; ++mt)
#pragma unroll
    for (int nt = 0; nt < 2; ++nt) {
      int col = bn * 64 + wn + nt * 16 + lm;
      float bv2 = bias[col];
#pragma unroll
      for (int r = 0; r < 4; ++r) {
        int row = bm * 128 + wm + mt * 16 + quad * 4 + r;
        C[(size_t)row * 512 + col] = acc[mt][nt][r] + bv2;
      }
    }
}

// ---------------------------------------------------------------------------
// bf16 MFMA GEMM (hi only, bf16 A): out projection
// ---------------------------------------------------------------------------
__global__ __launch_bounds__(256) void gemm_bf16(
    const ushort_t* __restrict__ A, const ushort_t* __restrict__ Bt,
    const float* __restrict__ bias, float* __restrict__ C) {
  __shared__ ushort_t As[128][32];  // 8 KB  [m][k]
  __shared__ ushort_t Bs[64][32];   // 4 KB  [n][k]
  int bm = blockIdx.x, bn = blockIdx.y;
  int tid = threadIdx.x;
  int wave = tid >> 6, lane = tid & 63;
  int wm = (wave & 1) * 64, wn = (wave >> 1) * 32;
  int quad = lane >> 4, lm = lane & 15;
  facc4 acc[4][2] = {};

  for (int k0 = 0; k0 < 512; k0 += 32) {
#pragma unroll
    for (int p = 0; p < 2; ++p) {
      int s = p * 256 + tid;
      int row = s >> 2, kq = (s & 3) * 8;
      *(bfrag8*)&As[row][kq] =
          *(const bfrag8*)&A[(size_t)(bm * 128 + row) * 512 + k0 + kq];
    }
    {
      int row = tid >> 2, kq = (tid & 3) * 8;
      *(bfrag8*)&Bs[row][kq] =
          *(const bfrag8*)&Bt[(size_t)(bn * 64 + row) * 512 + k0 + kq];
    }
    __syncthreads();
    bfrag8 af[4], bf[2];
#pragma unroll
    for (int mt = 0; mt < 4; ++mt)
      af[mt] = *(bfrag8*)&As[wm + mt * 16 + lm][quad * 8];
#pragma unroll
    for (int nt = 0; nt < 2; ++nt)
      bf[nt] = *(bfrag8*)&Bs[wn + nt * 16 + lm][quad * 8];
#pragma unroll
    for (int mt = 0; mt < 4; ++mt)
#pragma unroll
      for (int nt = 0; nt < 2; ++nt)
        acc[mt][nt] = __builtin_amdgcn_mfma_f32_16x16x32_bf16(
            af[mt], bf[nt], acc[mt][nt], 0, 0, 0);
    __syncthreads();
  }
#pragma unroll
  for (int mt = 0; mt < 4; ++mt)
#pragma unroll
    for (int nt = 0; nt < 2; ++nt) {
      int col = bn * 64 + wn + nt * 16 + lm;
      float bv = bias[col];
#pragma unroll
      for (int r = 0; r < 4; ++r) {
        int row = bm * 128 + wm + mt * 16 + quad * 4 + r;
        C[(size_t)row * 512 + col] = acc[mt][nt][r] + bv;
      }
    }
}

// ---------------------------------------------------------------------------
// m[b,h,l] = max_s(q.k_sample) - sum_s(q.k_sample)/L
// ---------------------------------------------------------------------------
__global__ __launch_bounds__(256) void compute_m(
    const float* __restrict__ q, const float* __restrict__ k,
    const int* __restrict__ idxs, float* __restrict__ m) {
  int wave = threadIdx.x >> 6, lane = threadIdx.x & 63;
  int lq = lane >> 4, dq = lane & 15;
  int slot = (blockIdx.x * 4 + wave) * 4 + lq;  // (b,h,l) flat
  int l = slot & (Lq - 1);
  int bh = slot >> 11;
  int h = bh & (Hq - 1), b = bh >> 3;
  float4 qv = *(const float4*)&q[((size_t)b * Lq + l) * Dq + h * DKq + dq * 4];
  const float* kb = &k[(size_t)b * Lq * Dq + h * DKq + dq * 4];
  const int* ib = &idxs[l * Uq];
  float mx = -INFINITY, sm = 0.f;
#pragma unroll
  for (int s = 0; s < Uq; ++s) {
    int j = ib[s];
    float4 kv = *(const float4*)&kb[(size_t)j * Dq];
    float p = qv.x * kv.x + qv.y * kv.y + qv.z * kv.z + qv.w * kv.w;
    p += __shfl_xor(p, 1, 64);
    p += __shfl_xor(p, 2, 64);
    p += __shfl_xor(p, 4, 64);
    p += __shfl_xor(p, 8, 64);
    mx = fmaxf(mx, p);
    sm += p;
  }
  if (dq == 0) m[slot] = mx - sm * (1.0f / Lq);
}

// ---------------------------------------------------------------------------
// top-24 per (b,h), two-stage bitonic on packed keys.
// ---------------------------------------------------------------------------
__device__ inline void bitonic256_desc(u64* s, int tid) {
  for (int k = 2; k <= 256; k <<= 1) {
    for (int j = k >> 1; j > 0; j >>= 1) {
      int p = tid ^ j;
      u64 mine = s[tid], other = s[p];
      u64 mx = mine > other ? mine : other;
      u64 mn = mine > other ? other : mine;
      bool dir = (tid & k) == 0;   // descending block
      bool lower = tid < p;
      u64 res = dir ? (lower ? mx : mn) : (lower ? mn : mx);
      __syncthreads();
      s[tid] = res;
      __syncthreads();
    }
  }
}

__global__ __launch_bounds__(256) void topk_stage1(
    const float* __restrict__ m, u64* __restrict__ cand) {
  __shared__ u64 s[256];
  int bh = blockIdx.x >> 3;      // 0..31
  int ch = blockIdx.x & 7;       // chunk 0..7
  int tid = threadIdx.x;
  int gidx = ch * 256 + tid;
  float v = m[(size_t)bh * Lq + gidx];
  s[tid] = ((u64)fkey(v) << 32) | (u64)(Lq - 1 - gidx);
  __syncthreads();
  bitonic256_desc(s, tid);
  if (tid < Uq) cand[((size_t)bh * TKCH + ch) * Uq + tid] = s[tid];
}

__global__ __launch_bounds__(256) void topk_stage2(
    const u64* __restrict__ cand, int* __restrict__ mtop) {
  __shared__ u64 s[256];
  int bh = blockIdx.x;
  int tid = threadIdx.x;
  s[tid] = (tid < TKCH * Uq) ? cand[(size_t)bh * TKCH * Uq + tid] : 0ull;
  __syncthreads();
  bitonic256_desc(s, tid);
  if (tid < Uq) mtop[bh * Uq + tid] = Lq - 1 - (int)(s[tid] & 0xFFFFFFFFull);
}

// ---------------------------------------------------------------------------
// repl[b,h,l] = u if l == mtop[b,h,u] else -1 (fill + match, one kernel)
// ---------------------------------------------------------------------------
__global__ __launch_bounds__(256) void make_repl(
    const int* __restrict__ mtop, int* __restrict__ repl) {
  __shared__ int mt[Uq];
  int bh = blockIdx.x >> 3;
  int ch = blockIdx.x & 7;
  int tid = threadIdx.x;
  if (tid < Uq) mt[tid] = mtop[bh * Uq + tid];
  __syncthreads();
  int l = ch * 256 + tid;
  int u = -1;
#pragma unroll
  for (int s = 0; s < Uq; ++s)
    if (mt[s] == l) u = s;
  repl[(size_t)bh * Lq + l] = u;
}

// ---------------------------------------------------------------------------
// scores[bh][u][j] = (q[b,i0[u],h,:] . k[b,j,h,:]) / sqrt(D)
// ---------------------------------------------------------------------------
#define JT 256
#define JS 64

__global__ __launch_bounds__(256) void scores_kernel(
    const float* __restrict__ q, const float* __restrict__ k,
    const int* __restrict__ mtop, float* __restrict__ scg) {
  __shared__ float qs[Uq][DKq + 1];
  __shared__ float ks[JS][DKq + 1];
  __shared__ int i0s[Uq];
  int bh = blockIdx.y;
  int jt = blockIdx.x;
  int h = bh & (Hq - 1);
  int b = bh >> 3;
  int tid = threadIdx.x;
  if (tid < Uq) i0s[tid] = mtop[bh * Uq + tid];
  __syncthreads();
  for (int s = tid; s < Uq * 16; s += 256) {
    int u = s >> 4, qd = (s & 15) * 4;
    float4 t = *(const float4*)&q[((size_t)b * Lq + i0s[u]) * Dq + h * DKq + qd];
    qs[u][qd] = t.x; qs[u][qd + 1] = t.y; qs[u][qd + 2] = t.z; qs[u][qd + 3] = t.w;
  }
  int jp = tid & 31;
  int ug = tid >> 5;
  const float scale = 0.044194173824159216f;  // 1/sqrt(512)
  for (int sub = 0; sub < JT / JS; ++sub) {
    int jbase = jt * JT + sub * JS;
    __syncthreads();
    for (int s = tid; s < JS * 16; s += 256) {
      int j = s >> 4, qd = (s & 15) * 4;
      float4 t = *(const float4*)&k[((size_t)b * Lq + jbase + j) * Dq + h * DKq + qd];
      ks[j][qd] = t.x; ks[j][qd + 1] = t.y; ks[j][qd + 2] = t.z; ks[j][qd + 3] = t.w;
    }
    __syncthreads();
    float acc[3][2] = {};
    int j0 = jp * 2, j1 = j0 + 1;
#pragma unroll 8
    for (int d = 0; d < DKq; ++d) {
      float k0 = ks[j0][d], k1 = ks[j1][d];
#pragma unroll
      for (int uu = 0; uu < 3; ++uu) {
        float qv = qs[ug * 3 + uu][d];
        acc[uu][0] += qv * k0;
        acc[uu][1] += qv * k1;
      }
    }
#pragma unroll
    for (int uu = 0; uu < 3; ++uu) {
      int u = ug * 3 + uu;
      scg[((size_t)(bh * Uq + u)) * Lq + jbase + j0] = acc[uu][0] * scale;
      scg[((size_t)(bh * Uq + u)) * Lq + jbase + j1] = acc[uu][1] * scale;
    }
  }
}

// ---------------------------------------------------------------------------
// softmax+PV, split over j-chunks of 256 for TLP.
// ---------------------------------------------------------------------------
__global__ __launch_bounds__(256) void softmax_pv_partial(
    const float* __restrict__ scg, const float* __restrict__ v,
    const int* __restrict__ mtop, float* __restrict__ pmax,
    float* __restrict__ psum, float* __restrict__ pvp) {
  int blk = blockIdx.y;  // bh*U + u
  int jc = blockIdx.x;
  int bh = blk / Uq;
  int h = bh & (Hq - 1);
  int b = bh >> 3;
  int n = mtop[blk] + 1;   // causal bound
  int j0 = jc * JCH;
  if (j0 >= n) return;
  int cnt = min(JCH, n - j0);
  int tid = threadIdx.x, wave = tid >> 6, lane = tid & 63;
  __shared__ float es[JCH];
  __shared__ float red[4][DKq];
  __shared__ float rr[4];

  const float* row = &scg[(size_t)blk * Lq + j0];
  float mx = (tid < cnt) ? row[tid] : -INFINITY;
#pragma unroll
  for (int off = 32; off; off >>= 1) mx = fmaxf(mx, __shfl_xor(mx, off, 64));
  if (lane == 0) rr[wave] = mx;
  __syncthreads();
  mx = fmaxf(fmaxf(rr[0], rr[1]), fmaxf(rr[2], rr[3]));
  __syncthreads();

  float e = (tid < cnt) ? __expf(row[tid] - mx) : 0.f;
  es[tid] = e;
  float sm = e;
#pragma unroll
  for (int off = 32; off; off >>= 1) sm += __shfl_xor(sm, off, 64);
  if (lane == 0) rr[wave] = sm;
  __syncthreads();

  float acc = 0.f;
  const float* vb = &v[((size_t)b * Lq + j0) * Dq + h * DKq + lane];
  int jlo = wave * 64;
  int jhi = min(jlo + 64, cnt);
#pragma unroll 4
  for (int j = jlo; j < jhi; ++j) acc += es[j] * vb[(size_t)j * Dq];
  red[wave][lane] = acc;
  __syncthreads();
  if (wave == 0) {
    if (lane == 0) {
      pmax[blk * NCH + jc] = mx;
      psum[blk * NCH + jc] = rr[0] + rr[1] + rr[2] + rr[3];
    }
    pvp[((size_t)blk * NCH + jc) * DKq + lane] =
        red[0][lane] + red[1][lane] + red[2][lane] + red[3][lane];
  }
}

__global__ __launch_bounds__(256) void softmax_pv_combine(
    const float* __restrict__ pmax, const float* __restrict__ psum,
    const float* __restrict__ pvp, const int* __restrict__ mtop,
    float* __restrict__ attnv) {
  int blk = blockIdx.x * 4 + (threadIdx.x >> 6);  // bh*U + u
  int lane = threadIdx.x & 63;
  int n = mtop[blk] + 1;
  int nc = (n + JCH - 1) / JCH;
  float gmax = -INFINITY;
  for (int c = 0; c < nc; ++c) gmax = fmaxf(gmax, pmax[blk * NCH + c]);
  float tot = 0.f, acc = 0.f;
  for (int c = 0; c < nc; ++c) {
    float w = __expf(pmax[blk * NCH + c] - gmax);
    tot += psum[blk * NCH + c] * w;
    acc += pvp[((size_t)blk * NCH + c) * DKq + lane] * w;
  }
  attnv[(size_t)blk * DKq + lane] = acc / tot;
}

// ---------------------------------------------------------------------------
// cumsum over L: tile sums, then build_context with inline exclusive
// prefix (parallel L2 loads) + scatter + direct bf16 output.
// ---------------------------------------------------------------------------
__global__ __launch_bounds__(128) void tile_sum(const float* __restrict__ v,
                                                float* __restrict__ tsum) {
  int blk = blockIdx.x;  // b*NTILE + tile
  int tile = blk & (NTILE - 1);
  int b = blk >> 7;
  int d4 = threadIdx.x;  // 0..127 (float4 column slice)
  float4 s = {0.f, 0.f, 0.f, 0.f};
  const float* base = &v[((size_t)b * Lq + tile * TSCAN) * Dq + d4 * 4];
#pragma unroll
  for (int r = 0; r < TSCAN; ++r) {
    float4 x = *(const float4*)&base[(size_t)r * Dq];
    s.x += x.x; s.y += x.y; s.z += x.z; s.w += x.w;
  }
  *(float4*)&tsum[((size_t)b * NTILE + tile) * Dq + d4 * 4] = s;
}

__global__ __launch_bounds__(128) void build_context(
    const float* __restrict__ v, const float* __restrict__ tsum,
    const int* __restrict__ repl, const float* __restrict__ attnv,
    ushort_t* __restrict__ ctxh) {
  int blk = blockIdx.x;  // b*NTILE + tile
  int tile = blk & (NTILE - 1);
  int b = blk >> 7;
  int d4 = threadIdx.x;          // float4 column slice
  int h = d4 >> 4;               // (d4*4)>>6
  // exclusive prefix over preceding tile sums (independent L2 loads)
  float4 run = {0.f, 0.f, 0.f, 0.f};
  const float* tb = &tsum[(size_t)b * NTILE * Dq + d4 * 4];
  for (int i = 0; i < tile; ++i) {
    float4 t = *(const float4*)&tb[(size_t)i * Dq];
    run.x += t.x; run.y += t.y; run.z += t.z; run.w += t.w;
  }
  const int* replb = &repl[(size_t)(b * Hq + h) * Lq + tile * TSCAN];
  const float* vb = &v[((size_t)b * Lq + tile * TSCAN) * Dq + d4 * 4];
  ushort_t* cb = &ctxh[((size_t)b * Lq + tile * TSCAN) * Dq + d4 * 4];
  const float* ab = &attnv[(size_t)(b * Hq + h) * Uq * DKq + (d4 & 15) * 4];
#pragma unroll
  for (int r = 0; r < TSCAN; ++r) {
    float4 x = *(const float4*)&vb[(size_t)r * Dq];
    run.x += x.x; run.y += x.y; run.z += x.z; run.w += x.w;
    int u = replb[r];
    float4 val = run;
    if (u >= 0) val = *(const float4*)&ab[(size_t)u * DKq];
    ushort4 o = {bf16_rne(val.x), bf16_rne(val.y), bf16_rne(val.z),
                 bf16_rne(val.w)};
    *(ushort4*)&cb[(size_t)r * Dq] = o;
  }
}

// ---------------------------------------------------------------------------
extern "C" void kernel_launch(void* const* d_in, const int* in_sizes, int n_in,
                              void* d_out, int out_size, void* d_ws,
                              size_t ws_size, hipStream_t stream) {
  const float* queries = (const float*)d_in[0];
  const float* keys    = (const float*)d_in[1];
  const float* values  = (const float*)d_in[2];
  const int*   idxs    = (const int*)d_in[3];
  const float* Wq = (const float*)d_in[4];
  const float* bq = (const float*)d_in[5];
  const float* Wk = (const float*)d_in[6];
  const float* bk = (const float*)d_in[7];
  const float* Wv = (const float*)d_in[8];
  const float* bv = (const float*)d_in[9];
  const float* Wo = (const float*)d_in[10];
  const float* bo = (const float*)d_in[11];
  float* out = (float*)d_out;

  const size_t BLD = (size_t)Bq * Lq * Dq;  // 4,194,304
  char* w = (char*)d_ws;
  float* q    = (float*)w; w += BLD * 4;
  float* k    = (float*)w; w += BLD * 4;
  float* v    = (float*)w; w += BLD * 4;
  float* scg  = (float*)w; w += (size_t)Bq * Hq * Uq * Lq * 4;  // 6.3 MB
  float* m    = (float*)w; w += (size_t)Bq * Hq * Lq * 4;
  float* attnv= (float*)w; w += (size_t)Bq * Hq * Uq * DKq * 4;
  float* tsum = (float*)w; w += (size_t)Bq * NTILE * Dq * 4;
  int* mtop   = (int*)w;   w += Bq * Hq * Uq * 4;
  int* repl   = (int*)w;   w += (size_t)Bq * Hq * Lq * 4;
  float* pmax = (float*)w; w += (size_t)Bq * Hq * Uq * NCH * 4;
  float* psum = (float*)w; w += (size_t)Bq * Hq * Uq * NCH * 4;
  float* pvp  = (float*)w; w += (size_t)Bq * Hq * Uq * NCH * DKq * 4;
  u64* cand   = (u64*)w;   w += (size_t)Bq * Hq * TKCH * Uq * 8;
  ushort_t* ctxh = (ushort_t*)w; w += BLD * 2;  // bf16 context
  const size_t WSZ = 512 * 512;
  ushort_t* Wqh = (ushort_t*)w; w += WSZ * 2;
  ushort_t* Wql = (ushort_t*)w; w += WSZ * 2;
  ushort_t* Wkh = (ushort_t*)w; w += WSZ * 2;
  ushort_t* Wkl = (ushort_t*)w; w += WSZ * 2;
  ushort_t* Wvh = (ushort_t*)w; w += WSZ * 2;
  ushort_t* Woh = (ushort_t*)w; w += WSZ * 2;

  // weights: transpose + hi/lo cast, one launch
  {
    dim3 tgrid(16, 16, 4);
    transpose_cast4<<<tgrid, 256, 0, stream>>>(Wq, Wk, Wv, Wo, Wqh, Wql, Wkh,
                                               Wkl, Wvh, Woh);
  }

  // fused Q/K/V projections (in-kernel hi/lo decompose of fp32 A)
  {
    dim3 ggrid(64, 8, 3);  // M=8192/128, N=512/64, z = Q/K/V
    gemm_qkv<<<ggrid, 256, 0, stream>>>(queries, keys, values, Wqh, Wql, Wkh,
                                        Wkl, Wvh, bq, bk, bv, q, k, v);
  }

  // sparsity metric + top-k (two-stage bitonic) + replacement table
  compute_m<<<(Bq * Hq * Lq) / 16, 256, 0, stream>>>(q, k, idxs, m);
  topk_stage1<<<Bq * Hq * TKCH, 256, 0, stream>>>(m, cand);
  topk_stage2<<<Bq * Hq, 256, 0, stream>>>(cand, mtop);
  make_repl<<<Bq * Hq * 8, 256, 0, stream>>>(mtop, repl);

  // attention on the top-24 rows
  {
    dim3 sgrid(Lq / JT, Bq * Hq);  // (8, 32)
    scores_kernel<<<sgrid, 256, 0, stream>>>(q, k, mtop, scg);
  }
  {
    dim3 pgrid(NCH, Bq * Hq * Uq);  // (8, 768)
    softmax_pv_partial<<<pgrid, 256, 0, stream>>>(scg, v, mtop, pmax, psum, pvp);
    softmax_pv_combine<<<Bq * Hq * Uq / 4, 256, 0, stream>>>(pmax, psum, pvp,
                                                             mtop, attnv);
  }

  // cumsum context + scatter, bf16 output (inline prefix — no tile_prefix)
  tile_sum<<<Bq * NTILE, 128, 0, stream>>>(v, tsum);
  build_context<<<Bq * NTILE, 128, 0, stream>>>(v, tsum, repl, attnv, ctxh);

  // output projection (plain bf16)
  {
    dim3 ggrid(64, 8);
    gemm_bf16<<<ggrid, 256, 0, stream>>>(ctxh, Woh, bo, out);
  }
}

// Round 8
// 302.395 us; speedup vs baseline: 1.0426x; 1.0426x over previous
//
#include <hip/hip_runtime.h>
#include <hip/hip_bf16.h>
#include <math.h>

#define Bq 4
#define Lq 2048
#define Dq 512
#define Hq 8
#define DKq 64
#define Uq 24
#define TSCAN 16
#define NTILE (Lq / TSCAN)   // 128
#define JCH 256              // softmax j-chunk
#define NCH (Lq / JCH)       // 8
#define TKCH 8               // top-k chunks per bh
#define PAD 40               // LDS row stride (ushorts): 80B -> bank period 8, <=2-way

typedef unsigned short ushort_t;
typedef unsigned long long u64;
typedef __attribute__((ext_vector_type(8))) short bfrag8;   // 8 bf16 (4 VGPRs)
typedef __attribute__((ext_vector_type(4))) float facc4;    // MFMA accumulator

__device__ inline ushort_t bf16_rne(float f) {
  unsigned u = __float_as_uint(f);
  u += 0x7FFF + ((u >> 16) & 1);
  return (ushort_t)(u >> 16);
}
__device__ inline float bf16f(ushort_t h) {
  return __uint_as_float(((unsigned)h) << 16);
}
// monotone float -> uint map (no NaNs in inputs)
__device__ inline unsigned fkey(float f) {
  unsigned u = __float_as_uint(f);
  return (u & 0x80000000u) ? ~u : (u | 0x80000000u);
}

// ---------------------------------------------------------------------------
// All 4 weights: fp32 [k][n] -> transposed bf16 hi/lo [n][k] (one launch)
// ---------------------------------------------------------------------------
__global__ __launch_bounds__(256) void transpose_cast4(
    const float* __restrict__ W0, const float* __restrict__ W1,
    const float* __restrict__ W2, const float* __restrict__ W3,
    ushort_t* __restrict__ T0h, ushort_t* __restrict__ T0l,
    ushort_t* __restrict__ T1h, ushort_t* __restrict__ T1l,
    ushort_t* __restrict__ T2h, ushort_t* __restrict__ T3h) {
  __shared__ float tile[32][33];
  int z = blockIdx.z;
  const float* W = z == 0 ? W0 : (z == 1 ? W1 : (z == 2 ? W2 : W3));
  ushort_t* Th = z == 0 ? T0h : (z == 1 ? T1h : (z == 2 ? T2h : T3h));
  ushort_t* Tl = z == 0 ? T0l : (z == 1 ? T1l : nullptr);
  int k0 = blockIdx.x * 32, n0 = blockIdx.y * 32;
  int tx = threadIdx.x & 31, ty = threadIdx.x >> 5;  // ty 0..7
  for (int r = ty; r < 32; r += 8)
    tile[tx][r] = W[(size_t)(k0 + r) * 512 + n0 + tx];
  __syncthreads();
  for (int r = ty; r < 32; r += 8) {
    float v = tile[r][tx];
    ushort_t h = bf16_rne(v);
    Th[(size_t)(n0 + r) * 512 + k0 + tx] = h;
    if (Tl) Tl[(size_t)(n0 + r) * 512 + k0 + tx] = bf16_rne(v - bf16f(h));
  }
}

// ---------------------------------------------------------------------------
// Fused Q/K/V projection GEMM, 128x128 tile, 4 waves x (64x64).
// z=0: Q (split-bf16), z=1: K (split), z=2: V (plain hi).
// fp32 A decomposed in staging; packed b128 LDS stores; PAD=40 rows.
// ---------------------------------------------------------------------------
__global__ __launch_bounds__(256) void gemm_qkv(
    const float* __restrict__ Xq, const float* __restrict__ Xk,
    const float* __restrict__ Xv,
    const ushort_t* __restrict__ Wqh, const ushort_t* __restrict__ Wql,
    const ushort_t* __restrict__ Wkh, const ushort_t* __restrict__ Wkl,
    const ushort_t* __restrict__ Wvh,
    const float* __restrict__ bq, const float* __restrict__ bk,
    const float* __restrict__ bv,
    float* __restrict__ qo, float* __restrict__ ko, float* __restrict__ vo) {
  __shared__ ushort_t Ash[128][PAD], Asl[128][PAD];  // 20 KB
  __shared__ ushort_t Bsh[128][PAD], Bsl[128][PAD];  // 20 KB
  int which = blockIdx.z;
  const float* A = which == 0 ? Xq : (which == 1 ? Xk : Xv);
  const ushort_t* Bh = which == 0 ? Wqh : (which == 1 ? Wkh : Wvh);
  const ushort_t* Bl = which == 0 ? Wql : Wkl;  // unused when which==2
  const float* bias = which == 0 ? bq : (which == 1 ? bk : bv);
  float* C = which == 0 ? qo : (which == 1 ? ko : vo);
  const bool split = which < 2;

  int bm = blockIdx.x, bn = blockIdx.y;
  int tid = threadIdx.x;
  int wave = tid >> 6, lane = tid & 63;
  int wm = (wave & 1) * 64, wn = (wave >> 1) * 64;
  int quad = lane >> 4, lm = lane & 15;
  facc4 acc[4][4] = {};

  for (int k0 = 0; k0 < 512; k0 += 32) {
    // A tile: 128 rows x 32 k -> 512 8-elem slots; 2 per thread
#pragma unroll
    for (int p = 0; p < 2; ++p) {
      int s = p * 256 + tid;
      int row = s >> 2, kq = (s & 3) * 8;
      const float* src = &A[(size_t)(bm * 128 + row) * 512 + k0 + kq];
      float4 x0 = *(const float4*)src;
      float4 x1 = *(const float4*)(src + 4);
      float xs[8] = {x0.x, x0.y, x0.z, x0.w, x1.x, x1.y, x1.z, x1.w};
      bfrag8 hv;
#pragma unroll
      for (int e = 0; e < 8; ++e) hv[e] = (short)bf16_rne(xs[e]);
      *(bfrag8*)&Ash[row][kq] = hv;   // single b128 store, conflict-free
      if (split) {
        bfrag8 lv;
#pragma unroll
        for (int e = 0; e < 8; ++e)
          lv[e] = (short)bf16_rne(xs[e] - bf16f((ushort_t)hv[e]));
        *(bfrag8*)&Asl[row][kq] = lv;
      }
    }
    // B tile: 128 n x 32 k, pre-converted bf16
#pragma unroll
    for (int p = 0; p < 2; ++p) {
      int s = p * 256 + tid;
      int row = s >> 2, kq = (s & 3) * 8;
      size_t g = (size_t)(bn * 128 + row) * 512 + k0 + kq;
      *(bfrag8*)&Bsh[row][kq] = *(const bfrag8*)&Bh[g];
      if (split) *(bfrag8*)&Bsl[row][kq] = *(const bfrag8*)&Bl[g];
    }
    __syncthreads();
    bfrag8 afh[4], afl[4], bfh[4], bfl[4];
#pragma unroll
    for (int mt = 0; mt < 4; ++mt) {
      afh[mt] = *(bfrag8*)&Ash[wm + mt * 16 + lm][quad * 8];
      if (split) afl[mt] = *(bfrag8*)&Asl[wm + mt * 16 + lm][quad * 8];
    }
#pragma unroll
    for (int nt = 0; nt < 4; ++nt) {
      bfh[nt] = *(bfrag8*)&Bsh[wn + nt * 16 + lm][quad * 8];
      if (split) bfl[nt] = *(bfrag8*)&Bsl[wn + nt * 16 + lm][quad * 8];
    }
#pragma unroll
    for (int mt = 0; mt < 4; ++mt)
#pragma unroll
      for (int nt = 0; nt < 4; ++nt) {
        facc4 a = acc[mt][nt];
        a = __builtin_amdgcn_mfma_f32_16x16x32_bf16(afh[mt], bfh[nt], a, 0, 0, 0);
        if (split) {
          a = __builtin_amdgcn_mfma_f32_16x16x32_bf16(afl[mt], bfh[nt], a, 0, 0, 0);
          a = __builtin_amdgcn_mfma_f32_16x16x32_bf16(afh[mt], bfl[nt], a, 0, 0, 0);
        }
        acc[mt][nt] = a;
      }
    __syncthreads();
  }
#pragma unroll
  for (int mt = 0; mt < 4; ++mt)
#pragma unroll
    for (int nt = 0; nt < 4; ++nt) {
      int col = bn * 128 + wn + nt * 16 + lm;
      float bv2 = bias[col];
#pragma unroll
      for (int r = 0; r < 4; ++r) {
        int row = bm * 128 + wm + mt * 16 + quad * 4 + r;
        C[(size_t)row * 512 + col] = acc[mt][nt][r] + bv2;
      }
    }
}

// ---------------------------------------------------------------------------
// bf16 MFMA GEMM (hi only, bf16 A): out projection, 128x128 tile
// ---------------------------------------------------------------------------
__global__ __launch_bounds__(256) void gemm_bf16(
    const ushort_t* __restrict__ A, const ushort_t* __restrict__ Bt,
    const float* __restrict__ bias, float* __restrict__ C) {
  __shared__ ushort_t As[128][PAD];  // 10 KB
  __shared__ ushort_t Bs[128][PAD];  // 10 KB
  int bm = blockIdx.x, bn = blockIdx.y;
  int tid = threadIdx.x;
  int wave = tid >> 6, lane = tid & 63;
  int wm = (wave & 1) * 64, wn = (wave >> 1) * 64;
  int quad = lane >> 4, lm = lane & 15;
  facc4 acc[4][4] = {};

  for (int k0 = 0; k0 < 512; k0 += 32) {
#pragma unroll
    for (int p = 0; p < 2; ++p) {
      int s = p * 256 + tid;
      int row = s >> 2, kq = (s & 3) * 8;
      *(bfrag8*)&As[row][kq] =
          *(const bfrag8*)&A[(size_t)(bm * 128 + row) * 512 + k0 + kq];
      *(bfrag8*)&Bs[row][kq] =
          *(const bfrag8*)&Bt[(size_t)(bn * 128 + row) * 512 + k0 + kq];
    }
    __syncthreads();
    bfrag8 af[4], bf[4];
#pragma unroll
    for (int mt = 0; mt < 4; ++mt)
      af[mt] = *(bfrag8*)&As[wm + mt * 16 + lm][quad * 8];
#pragma unroll
    for (int nt = 0; nt < 4; ++nt)
      bf[nt] = *(bfrag8*)&Bs[wn + nt * 16 + lm][quad * 8];
#pragma unroll
    for (int mt = 0; mt < 4; ++mt)
#pragma unroll
      for (int nt = 0; nt < 4; ++nt)
        acc[mt][nt] = __builtin_amdgcn_mfma_f32_16x16x32_bf16(
            af[mt], bf[nt], acc[mt][nt], 0, 0, 0);
    __syncthreads();
  }
#pragma unroll
  for (int mt = 0; mt < 4; ++mt)
#pragma unroll
    for (int nt = 0; nt < 4; ++nt) {
      int col = bn * 128 + wn + nt * 16 + lm;
      float bv = bias[col];
#pragma unroll
      for (int r = 0; r < 4; ++r) {
        int row = bm * 128 + wm + mt * 16 + quad * 4 + r;
        C[(size_t)row * 512 + col] = acc[mt][nt][r] + bv;
      }
    }
}

// ---------------------------------------------------------------------------
// m[b,h,l] = max_s(q.k_sample) - sum_s(q.k_sample)/L
// ---------------------------------------------------------------------------
__global__ __launch_bounds__(256) void compute_m(
    const float* __restrict__ q, const float* __restrict__ k,
    const int* __restrict__ idxs, float* __restrict__ m) {
  int wave = threadIdx.x >> 6, lane = threadIdx.x & 63;
  int lq = lane >> 4, dq = lane & 15;
  int slot = (blockIdx.x * 4 + wave) * 4 + lq;  // (b,h,l) flat
  int l = slot & (Lq - 1);
  int bh = slot >> 11;
  int h = bh & (Hq - 1), b = bh >> 3;
  float4 qv = *(const float4*)&q[((size_t)b * Lq + l) * Dq + h * DKq + dq * 4];
  const float* kb = &k[(size_t)b * Lq * Dq + h * DKq + dq * 4];
  const int* ib = &idxs[l * Uq];
  float mx = -INFINITY, sm = 0.f;
#pragma unroll
  for (int s = 0; s < Uq; ++s) {
    int j = ib[s];
    float4 kv = *(const float4*)&kb[(size_t)j * Dq];
    float p = qv.x * kv.x + qv.y * kv.y + qv.z * kv.z + qv.w * kv.w;
    p += __shfl_xor(p, 1, 64);
    p += __shfl_xor(p, 2, 64);
    p += __shfl_xor(p, 4, 64);
    p += __shfl_xor(p, 8, 64);
    mx = fmaxf(mx, p);
    sm += p;
  }
  if (dq == 0) m[slot] = mx - sm * (1.0f / Lq);
}

// ---------------------------------------------------------------------------
// top-24 per (b,h), two-stage bitonic on packed keys.
// ---------------------------------------------------------------------------
__device__ inline void bitonic256_desc(u64* s, int tid) {
  for (int k = 2; k <= 256; k <<= 1) {
    for (int j = k >> 1; j > 0; j >>= 1) {
      int p = tid ^ j;
      u64 mine = s[tid], other = s[p];
      u64 mx = mine > other ? mine : other;
      u64 mn = mine > other ? other : mine;
      bool dir = (tid & k) == 0;   // descending block
      bool lower = tid < p;
      u64 res = dir ? (lower ? mx : mn) : (lower ? mn : mx);
      __syncthreads();
      s[tid] = res;
      __syncthreads();
    }
  }
}

__global__ __launch_bounds__(256) void topk_stage1(
    const float* __restrict__ m, u64* __restrict__ cand) {
  __shared__ u64 s[256];
  int bh = blockIdx.x >> 3;      // 0..31
  int ch = blockIdx.x & 7;       // chunk 0..7
  int tid = threadIdx.x;
  int gidx = ch * 256 + tid;
  float v = m[(size_t)bh * Lq + gidx];
  s[tid] = ((u64)fkey(v) << 32) | (u64)(Lq - 1 - gidx);
  __syncthreads();
  bitonic256_desc(s, tid);
  if (tid < Uq) cand[((size_t)bh * TKCH + ch) * Uq + tid] = s[tid];
}

__global__ __launch_bounds__(256) void topk_stage2(
    const u64* __restrict__ cand, int* __restrict__ mtop) {
  __shared__ u64 s[256];
  int bh = blockIdx.x;
  int tid = threadIdx.x;
  s[tid] = (tid < TKCH * Uq) ? cand[(size_t)bh * TKCH * Uq + tid] : 0ull;
  __syncthreads();
  bitonic256_desc(s, tid);
  if (tid < Uq) mtop[bh * Uq + tid] = Lq - 1 - (int)(s[tid] & 0xFFFFFFFFull);
}

// ---------------------------------------------------------------------------
// repl[b,h,l] = u if l == mtop[b,h,u] else -1 (fill + match, one kernel)
// ---------------------------------------------------------------------------
__global__ __launch_bounds__(256) void make_repl(
    const int* __restrict__ mtop, int* __restrict__ repl) {
  __shared__ int mt[Uq];
  int bh = blockIdx.x >> 3;
  int ch = blockIdx.x & 7;
  int tid = threadIdx.x;
  if (tid < Uq) mt[tid] = mtop[bh * Uq + tid];
  __syncthreads();
  int l = ch * 256 + tid;
  int u = -1;
#pragma unroll
  for (int s = 0; s < Uq; ++s)
    if (mt[s] == l) u = s;
  repl[(size_t)bh * Lq + l] = u;
}

// ---------------------------------------------------------------------------
// scores[bh][u][j] = (q[b,i0[u],h,:] . k[b,j,h,:]) / sqrt(D)
// ---------------------------------------------------------------------------
#define JT 256
#define JS 64

__global__ __launch_bounds__(256) void scores_kernel(
    const float* __restrict__ q, const float* __restrict__ k,
    const int* __restrict__ mtop, float* __restrict__ scg) {
  __shared__ float qs[Uq][DKq + 1];
  __shared__ float ks[JS][DKq + 1];
  __shared__ int i0s[Uq];
  int bh = blockIdx.y;
  int jt = blockIdx.x;
  int h = bh & (Hq - 1);
  int b = bh >> 3;
  int tid = threadIdx.x;
  if (tid < Uq) i0s[tid] = mtop[bh * Uq + tid];
  __syncthreads();
  for (int s = tid; s < Uq * 16; s += 256) {
    int u = s >> 4, qd = (s & 15) * 4;
    float4 t = *(const float4*)&q[((size_t)b * Lq + i0s[u]) * Dq + h * DKq + qd];
    qs[u][qd] = t.x; qs[u][qd + 1] = t.y; qs[u][qd + 2] = t.z; qs[u][qd + 3] = t.w;
  }
  int jp = tid & 31;
  int ug = tid >> 5;
  const float scale = 0.044194173824159216f;  // 1/sqrt(512)
  for (int sub = 0; sub < JT / JS; ++sub) {
    int jbase = jt * JT + sub * JS;
    __syncthreads();
    for (int s = tid; s < JS * 16; s += 256) {
      int j = s >> 4, qd = (s & 15) * 4;
      float4 t = *(const float4*)&k[((size_t)b * Lq + jbase + j) * Dq + h * DKq + qd];
      ks[j][qd] = t.x; ks[j][qd + 1] = t.y; ks[j][qd + 2] = t.z; ks[j][qd + 3] = t.w;
    }
    __syncthreads();
    float acc[3][2] = {};
    int j0 = jp * 2, j1 = j0 + 1;
#pragma unroll 8
    for (int d = 0; d < DKq; ++d) {
      float k0 = ks[j0][d], k1 = ks[j1][d];
#pragma unroll
      for (int uu = 0; uu < 3; ++uu) {
        float qv = qs[ug * 3 + uu][d];
        acc[uu][0] += qv * k0;
        acc[uu][1] += qv * k1;
      }
    }
#pragma unroll
    for (int uu = 0; uu < 3; ++uu) {
      int u = ug * 3 + uu;
      scg[((size_t)(bh * Uq + u)) * Lq + jbase + j0] = acc[uu][0] * scale;
      scg[((size_t)(bh * Uq + u)) * Lq + jbase + j1] = acc[uu][1] * scale;
    }
  }
}

// ---------------------------------------------------------------------------
// softmax+PV, split over j-chunks of 256 for TLP.
// ---------------------------------------------------------------------------
__global__ __launch_bounds__(256) void softmax_pv_partial(
    const float* __restrict__ scg, const float* __restrict__ v,
    const int* __restrict__ mtop, float* __restrict__ pmax,
    float* __restrict__ psum, float* __restrict__ pvp) {
  int blk = blockIdx.y;  // bh*U + u
  int jc = blockIdx.x;
  int bh = blk / Uq;
  int h = bh & (Hq - 1);
  int b = bh >> 3;
  int n = mtop[blk] + 1;   // causal bound
  int j0 = jc * JCH;
  if (j0 >= n) return;
  int cnt = min(JCH, n - j0);
  int tid = threadIdx.x, wave = tid >> 6, lane = tid & 63;
  __shared__ float es[JCH];
  __shared__ float red[4][DKq];
  __shared__ float rr[4];

  const float* row = &scg[(size_t)blk * Lq + j0];
  float mx = (tid < cnt) ? row[tid] : -INFINITY;
#pragma unroll
  for (int off = 32; off; off >>= 1) mx = fmaxf(mx, __shfl_xor(mx, off, 64));
  if (lane == 0) rr[wave] = mx;
  __syncthreads();
  mx = fmaxf(fmaxf(rr[0], rr[1]), fmaxf(rr[2], rr[3]));
  __syncthreads();

  float e = (tid < cnt) ? __expf(row[tid] - mx) : 0.f;
  es[tid] = e;
  float sm = e;
#pragma unroll
  for (int off = 32; off; off >>= 1) sm += __shfl_xor(sm, off, 64);
  if (lane == 0) rr[wave] = sm;
  __syncthreads();

  float acc = 0.f;
  const float* vb = &v[((size_t)b * Lq + j0) * Dq + h * DKq + lane];
  int jlo = wave * 64;
  int jhi = min(jlo + 64, cnt);
#pragma unroll 4
  for (int j = jlo; j < jhi; ++j) acc += es[j] * vb[(size_t)j * Dq];
  red[wave][lane] = acc;
  __syncthreads();
  if (wave == 0) {
    if (lane == 0) {
      pmax[blk * NCH + jc] = mx;
      psum[blk * NCH + jc] = rr[0] + rr[1] + rr[2] + rr[3];
    }
    pvp[((size_t)blk * NCH + jc) * DKq + lane] =
        red[0][lane] + red[1][lane] + red[2][lane] + red[3][lane];
  }
}

__global__ __launch_bounds__(256) void softmax_pv_combine(
    const float* __restrict__ pmax, const float* __restrict__ psum,
    const float* __restrict__ pvp, const int* __restrict__ mtop,
    float* __restrict__ attnv) {
  int blk = blockIdx.x * 4 + (threadIdx.x >> 6);  // bh*U + u
  int lane = threadIdx.x & 63;
  int n = mtop[blk] + 1;
  int nc = (n + JCH - 1) / JCH;
  float gmax = -INFINITY;
  for (int c = 0; c < nc; ++c) gmax = fmaxf(gmax, pmax[blk * NCH + c]);
  float tot = 0.f, acc = 0.f;
  for (int c = 0; c < nc; ++c) {
    float w = __expf(pmax[blk * NCH + c] - gmax);
    tot += psum[blk * NCH + c] * w;
    acc += pvp[((size_t)blk * NCH + c) * DKq + lane] * w;
  }
  attnv[(size_t)blk * DKq + lane] = acc / tot;
}

// ---------------------------------------------------------------------------
// cumsum over L: tile sums, then build_context with inline exclusive
// prefix (parallel L2 loads) + scatter + direct bf16 output.
// ---------------------------------------------------------------------------
__global__ __launch_bounds__(128) void tile_sum(const float* __restrict__ v,
                                                float* __restrict__ tsum) {
  int blk = blockIdx.x;  // b*NTILE + tile
  int tile = blk & (NTILE - 1);
  int b = blk >> 7;
  int d4 = threadIdx.x;  // 0..127 (float4 column slice)
  float4 s = {0.f, 0.f, 0.f, 0.f};
  const float* base = &v[((size_t)b * Lq + tile * TSCAN) * Dq + d4 * 4];
#pragma unroll
  for (int r = 0; r < TSCAN; ++r) {
    float4 x = *(const float4*)&base[(size_t)r * Dq];
    s.x += x.x; s.y += x.y; s.z += x.z; s.w += x.w;
  }
  *(float4*)&tsum[((size_t)b * NTILE + tile) * Dq + d4 * 4] = s;
}

__global__ __launch_bounds__(128) void build_context(
    const float* __restrict__ v, const float* __restrict__ tsum,
    const int* __restrict__ repl, const float* __restrict__ attnv,
    ushort_t* __restrict__ ctxh) {
  int blk = blockIdx.x;  // b*NTILE + tile
  int tile = blk & (NTILE - 1);
  int b = blk >> 7;
  int d4 = threadIdx.x;          // float4 column slice
  int h = d4 >> 4;               // (d4*4)>>6
  // exclusive prefix over preceding tile sums (independent L2 loads)
  float4 run = {0.f, 0.f, 0.f, 0.f};
  const float* tb = &tsum[(size_t)b * NTILE * Dq + d4 * 4];
  for (int i = 0; i < tile; ++i) {
    float4 t = *(const float4*)&tb[(size_t)i * Dq];
    run.x += t.x; run.y += t.y; run.z += t.z; run.w += t.w;
  }
  const int* replb = &repl[(size_t)(b * Hq + h) * Lq + tile * TSCAN];
  const float* vb = &v[((size_t)b * Lq + tile * TSCAN) * Dq + d4 * 4];
  ushort_t* cb = &ctxh[((size_t)b * Lq + tile * TSCAN) * Dq + d4 * 4];
  const float* ab = &attnv[(size_t)(b * Hq + h) * Uq * DKq + (d4 & 15) * 4];
#pragma unroll
  for (int r = 0; r < TSCAN; ++r) {
    float4 x = *(const float4*)&vb[(size_t)r * Dq];
    run.x += x.x; run.y += x.y; run.z += x.z; run.w += x.w;
    int u = replb[r];
    float4 val = run;
    if (u >= 0) val = *(const float4*)&ab[(size_t)u * DKq];
    ushort4 o = {bf16_rne(val.x), bf16_rne(val.y), bf16_rne(val.z),
                 bf16_rne(val.w)};
    *(ushort4*)&cb[(size_t)r * Dq] = o;
  }
}

// ---------------------------------------------------------------------------
extern "C" void kernel_launch(void* const* d_in, const int* in_sizes, int n_in,
                              void* d_out, int out_size, void* d_ws,
                              size_t ws_size, hipStream_t stream) {
  const float* queries = (const float*)d_in[0];
  const float* keys    = (const float*)d_in[1];
  const float* values  = (const float*)d_in[2];
  const int*   idxs    = (const int*)d_in[3];
  const float* Wq = (const float*)d_in[4];
  const float* bq = (const float*)d_in[5];
  const float* Wk = (const float*)d_in[6];
  const float* bk = (const float*)d_in[7];
  const float* Wv = (const float*)d_in[8];
  const float* bv = (const float*)d_in[9];
  const float* Wo = (const float*)d_in[10];
  const float* bo = (const float*)d_in[11];
  float* out = (float*)d_out;

  const size_t BLD = (size_t)Bq * Lq * Dq;  // 4,194,304
  char* w = (char*)d_ws;
  float* q    = (float*)w; w += BLD * 4;
  float* k    = (float*)w; w += BLD * 4;
  float* v    = (float*)w; w += BLD * 4;
  float* scg  = (float*)w; w += (size_t)Bq * Hq * Uq * Lq * 4;  // 6.3 MB
  float* m    = (float*)w; w += (size_t)Bq * Hq * Lq * 4;
  float* attnv= (float*)w; w += (size_t)Bq * Hq * Uq * DKq * 4;
  float* tsum = (float*)w; w += (size_t)Bq * NTILE * Dq * 4;
  int* mtop   = (int*)w;   w += Bq * Hq * Uq * 4;
  int* repl   = (int*)w;   w += (size_t)Bq * Hq * Lq * 4;
  float* pmax = (float*)w; w += (size_t)Bq * Hq * Uq * NCH * 4;
  float* psum = (float*)w; w += (size_t)Bq * Hq * Uq * NCH * 4;
  float* pvp  = (float*)w; w += (size_t)Bq * Hq * Uq * NCH * DKq * 4;
  u64* cand   = (u64*)w;   w += (size_t)Bq * Hq * TKCH * Uq * 8;
  ushort_t* ctxh = (ushort_t*)w; w += BLD * 2;  // bf16 context
  const size_t WSZ = 512 * 512;
  ushort_t* Wqh = (ushort_t*)w; w += WSZ * 2;
  ushort_t* Wql = (ushort_t*)w; w += WSZ * 2;
  ushort_t* Wkh = (ushort_t*)w; w += WSZ * 2;
  ushort_t* Wkl = (ushort_t*)w; w += WSZ * 2;
  ushort_t* Wvh = (ushort_t*)w; w += WSZ * 2;
  ushort_t* Woh = (ushort_t*)w; w += WSZ * 2;

  // weights: transpose + hi/lo cast, one launch
  {
    dim3 tgrid(16, 16, 4);
    transpose_cast4<<<tgrid, 256, 0, stream>>>(Wq, Wk, Wv, Wo, Wqh, Wql, Wkh,
                                               Wkl, Wvh, Woh);
  }

  // fused Q/K/V projections (128x128 tiles, in-kernel hi/lo decompose)
  {
    dim3 ggrid(64, 4, 3);  // M=8192/128, N=512/128, z = Q/K/V
    gemm_qkv<<<ggrid, 256, 0, stream>>>(queries, keys, values, Wqh, Wql, Wkh,
                                        Wkl, Wvh, bq, bk, bv, q, k, v);
  }

  // sparsity metric + top-k (two-stage bitonic) + replacement table
  compute_m<<<(Bq * Hq * Lq) / 16, 256, 0, stream>>>(q, k, idxs, m);
  topk_stage1<<<Bq * Hq * TKCH, 256, 0, stream>>>(m, cand);
  topk_stage2<<<Bq * Hq, 256, 0, stream>>>(cand, mtop);
  make_repl<<<Bq * Hq * 8, 256, 0, stream>>>(mtop, repl);

  // attention on the top-24 rows
  {
    dim3 sgrid(Lq / JT, Bq * Hq);  // (8, 32)
    scores_kernel<<<sgrid, 256, 0, stream>>>(q, k, mtop, scg);
  }
  {
    dim3 pgrid(NCH, Bq * Hq * Uq);  // (8, 768)
    softmax_pv_partial<<<pgrid, 256, 0, stream>>>(scg, v, mtop, pmax, psum, pvp);
    softmax_pv_combine<<<Bq * Hq * Uq / 4, 256, 0, stream>>>(pmax, psum, pvp,
                                                             mtop, attnv);
  }

  // cumsum context + scatter, bf16 output (inline prefix — no tile_prefix)
  tile_sum<<<Bq * NTILE, 128, 0, stream>>>(v, tsum);
  build_context<<<Bq * NTILE, 128, 0, stream>>>(v, tsum, repl, attnv, ctxh);

  // output projection (plain bf16, 128x128 tiles)
  {
    dim3 ggrid(64, 4);
    gemm_bf16<<<ggrid, 256, 0, stream>>>(ctxh, Woh, bo, out);
  }
}

// Round 9
// 299.697 us; speedup vs baseline: 1.0520x; 1.0090x over previous
//
#include <hip/hip_runtime.h>
#include <hip/hip_bf16.h>
#include <math.h>

#define Bq 4
#define Lq 2048
#define Dq 512
#define Hq 8
#define DKq 64
#define Uq 24
#define TSCAN 16
#define NTILE (Lq / TSCAN)   // 128
#define JCH 256              // softmax j-chunk
#define NCH (Lq / JCH)       // 8
#define TKCH 8               // top-k chunks per bh

typedef unsigned short ushort_t;
typedef unsigned long long u64;
typedef __attribute__((ext_vector_type(8))) short bfrag8;   // 8 bf16 (4 VGPRs)
typedef __attribute__((ext_vector_type(4))) float facc4;    // MFMA accumulator

__device__ inline ushort_t bf16_rne(float f) {
  unsigned u = __float_as_uint(f);
  u += 0x7FFF + ((u >> 16) & 1);
  return (ushort_t)(u >> 16);
}
__device__ inline float bf16f(ushort_t h) {
  return __uint_as_float(((unsigned)h) << 16);
}
// monotone float -> uint map (no NaNs in inputs)
__device__ inline unsigned fkey(float f) {
  unsigned u = __float_as_uint(f);
  return (u & 0x80000000u) ? ~u : (u | 0x80000000u);
}
// async global->LDS, 16B per lane (lds dest = wave base + lane*16)
__device__ __forceinline__ void gl2lds16(const void* g, void* l) {
  __builtin_amdgcn_global_load_lds(
      (const __attribute__((address_space(1))) unsigned*)g,
      (__attribute__((address_space(3))) unsigned*)l, 16, 0, 0);
}

// ---------------------------------------------------------------------------
// cast fp32 -> (bf16 hi, bf16 lo); and hi-only variant
// ---------------------------------------------------------------------------
__global__ __launch_bounds__(256) void cast_hilo(
    const float* __restrict__ x, ushort_t* __restrict__ hi,
    ushort_t* __restrict__ lo, int n4) {
  int t = blockIdx.x * 256 + threadIdx.x;
  if (t >= n4) return;
  float4 v = *(const float4*)&x[(size_t)t * 4];
  ushort_t h0 = bf16_rne(v.x), h1 = bf16_rne(v.y), h2 = bf16_rne(v.z),
           h3 = bf16_rne(v.w);
  ushort4 hh = {h0, h1, h2, h3};
  ushort4 ll = {bf16_rne(v.x - bf16f(h0)), bf16_rne(v.y - bf16f(h1)),
                bf16_rne(v.z - bf16f(h2)), bf16_rne(v.w - bf16f(h3))};
  *(ushort4*)&hi[(size_t)t * 4] = hh;
  *(ushort4*)&lo[(size_t)t * 4] = ll;
}

__global__ __launch_bounds__(256) void cast_hi(
    const float* __restrict__ x, ushort_t* __restrict__ hi, int n4) {
  int t = blockIdx.x * 256 + threadIdx.x;
  if (t >= n4) return;
  float4 v = *(const float4*)&x[(size_t)t * 4];
  ushort4 hh = {bf16_rne(v.x), bf16_rne(v.y), bf16_rne(v.z), bf16_rne(v.w)};
  *(ushort4*)&hi[(size_t)t * 4] = hh;
}

// ---------------------------------------------------------------------------
// All 4 weights: fp32 [k][n] -> transposed bf16 hi/lo [n][k] (one launch)
// ---------------------------------------------------------------------------
__global__ __launch_bounds__(256) void transpose_cast4(
    const float* __restrict__ W0, const float* __restrict__ W1,
    const float* __restrict__ W2, const float* __restrict__ W3,
    ushort_t* __restrict__ T0h, ushort_t* __restrict__ T0l,
    ushort_t* __restrict__ T1h, ushort_t* __restrict__ T1l,
    ushort_t* __restrict__ T2h, ushort_t* __restrict__ T3h) {
  __shared__ float tile[32][33];
  int z = blockIdx.z;
  const float* W = z == 0 ? W0 : (z == 1 ? W1 : (z == 2 ? W2 : W3));
  ushort_t* Th = z == 0 ? T0h : (z == 1 ? T1h : (z == 2 ? T2h : T3h));
  ushort_t* Tl = z == 0 ? T0l : (z == 1 ? T1l : nullptr);
  int k0 = blockIdx.x * 32, n0 = blockIdx.y * 32;
  int tx = threadIdx.x & 31, ty = threadIdx.x >> 5;  // ty 0..7
  for (int r = ty; r < 32; r += 8)
    tile[tx][r] = W[(size_t)(k0 + r) * 512 + n0 + tx];
  __syncthreads();
  for (int r = ty; r < 32; r += 8) {
    float v = tile[r][tx];
    ushort_t h = bf16_rne(v);
    Th[(size_t)(n0 + r) * 512 + k0 + tx] = h;
    if (Tl) Tl[(size_t)(n0 + r) * 512 + k0 + tx] = bf16_rne(v - bf16f(h));
  }
}

// ---------------------------------------------------------------------------
// Fused Q/K/V projection GEMM, 128x128 tile, 4 waves x (64x64).
// z=0: Q (split-bf16), z=1: K (split), z=2: V (plain hi).
// Pre-cast bf16 inputs; async global_load_lds staging; m97 [128][32] layout.
// ---------------------------------------------------------------------------
__global__ __launch_bounds__(256) void gemm_qkv(
    const ushort_t* __restrict__ Aqh, const ushort_t* __restrict__ Aql,
    const ushort_t* __restrict__ Akh, const ushort_t* __restrict__ Akl,
    const ushort_t* __restrict__ Avh,
    const ushort_t* __restrict__ Wqh, const ushort_t* __restrict__ Wql,
    const ushort_t* __restrict__ Wkh, const ushort_t* __restrict__ Wkl,
    const ushort_t* __restrict__ Wvh,
    const float* __restrict__ bq, const float* __restrict__ bk,
    const float* __restrict__ bv,
    float* __restrict__ qo, float* __restrict__ ko, float* __restrict__ vo) {
  __shared__ ushort_t Ash[128][32], Asl[128][32];  // 8 KB each
  __shared__ ushort_t Bsh[128][32], Bsl[128][32];
  int which = blockIdx.z;
  const ushort_t* Ah = which == 0 ? Aqh : (which == 1 ? Akh : Avh);
  const ushort_t* Al = which == 0 ? Aql : Akl;  // unused for V
  const ushort_t* Bh = which == 0 ? Wqh : (which == 1 ? Wkh : Wvh);
  const ushort_t* Bl = which == 0 ? Wql : Wkl;
  const float* bias = which == 0 ? bq : (which == 1 ? bk : bv);
  float* C = which == 0 ? qo : (which == 1 ? ko : vo);
  const bool split = which < 2;

  int bm = blockIdx.x, bn = blockIdx.y;
  int tid = threadIdx.x;
  int wave = tid >> 6, lane = tid & 63;
  int wm = (wave & 1) * 64, wn = (wave >> 1) * 64;
  int quad = lane >> 4, lm = lane & 15;
  int srow = tid >> 2, skq = (tid & 3) * 8;   // staging slot (s = tid, tid+256)
  facc4 acc[4][4] = {};

  for (int k0 = 0; k0 < 512; k0 += 32) {
    // async staging: LDS offset = s*16B per lane (contiguous in lane order)
#pragma unroll
    for (int p = 0; p < 2; ++p) {
      int row = srow + p * 64;
      size_t ga = (size_t)(bm * 128 + row) * 512 + k0 + skq;
      size_t gb = (size_t)(bn * 128 + row) * 512 + k0 + skq;
      gl2lds16(&Ah[ga], &Ash[row][skq]);
      gl2lds16(&Bh[gb], &Bsh[row][skq]);
      if (split) {
        gl2lds16(&Al[ga], &Asl[row][skq]);
        gl2lds16(&Bl[gb], &Bsl[row][skq]);
      }
    }
    __syncthreads();
    bfrag8 afh[4], afl[4], bfh[4], bfl[4];
#pragma unroll
    for (int mt = 0; mt < 4; ++mt) {
      afh[mt] = *(bfrag8*)&Ash[wm + mt * 16 + lm][quad * 8];
      if (split) afl[mt] = *(bfrag8*)&Asl[wm + mt * 16 + lm][quad * 8];
    }
#pragma unroll
    for (int nt = 0; nt < 4; ++nt) {
      bfh[nt] = *(bfrag8*)&Bsh[wn + nt * 16 + lm][quad * 8];
      if (split) bfl[nt] = *(bfrag8*)&Bsl[wn + nt * 16 + lm][quad * 8];
    }
#pragma unroll
    for (int mt = 0; mt < 4; ++mt)
#pragma unroll
      for (int nt = 0; nt < 4; ++nt) {
        facc4 a = acc[mt][nt];
        a = __builtin_amdgcn_mfma_f32_16x16x32_bf16(afh[mt], bfh[nt], a, 0, 0, 0);
        if (split) {
          a = __builtin_amdgcn_mfma_f32_16x16x32_bf16(afl[mt], bfh[nt], a, 0, 0, 0);
          a = __builtin_amdgcn_mfma_f32_16x16x32_bf16(afh[mt], bfl[nt], a, 0, 0, 0);
        }
        acc[mt][nt] = a;
      }
    __syncthreads();
  }
#pragma unroll
  for (int mt = 0; mt < 4; ++mt)
#pragma unroll
    for (int nt = 0; nt < 4; ++nt) {
      int col = bn * 128 + wn + nt * 16 + lm;
      float bv2 = bias[col];
#pragma unroll
      for (int r = 0; r < 4; ++r) {
        int row = bm * 128 + wm + mt * 16 + quad * 4 + r;
        C[(size_t)row * 512 + col] = acc[mt][nt][r] + bv2;
      }
    }
}

// ---------------------------------------------------------------------------
// bf16 MFMA GEMM (hi only, bf16 A): out projection, 128x128 tile, async stage
// ---------------------------------------------------------------------------
__global__ __launch_bounds__(256) void gemm_bf16(
    const ushort_t* __restrict__ A, const ushort_t* __restrict__ Bt,
    const float* __restrict__ bias, float* __restrict__ C) {
  __shared__ ushort_t As[128][32];
  __shared__ ushort_t Bs[128][32];
  int bm = blockIdx.x, bn = blockIdx.y;
  int tid = threadIdx.x;
  int wave = tid >> 6, lane = tid & 63;
  int wm = (wave & 1) * 64, wn = (wave >> 1) * 64;
  int quad = lane >> 4, lm = lane & 15;
  int srow = tid >> 2, skq = (tid & 3) * 8;
  facc4 acc[4][4] = {};

  for (int k0 = 0; k0 < 512; k0 += 32) {
#pragma unroll
    for (int p = 0; p < 2; ++p) {
      int row = srow + p * 64;
      gl2lds16(&A[(size_t)(bm * 128 + row) * 512 + k0 + skq], &As[row][skq]);
      gl2lds16(&Bt[(size_t)(bn * 128 + row) * 512 + k0 + skq], &Bs[row][skq]);
    }
    __syncthreads();
    bfrag8 af[4], bf[4];
#pragma unroll
    for (int mt = 0; mt < 4; ++mt)
      af[mt] = *(bfrag8*)&As[wm + mt * 16 + lm][quad * 8];
#pragma unroll
    for (int nt = 0; nt < 4; ++nt)
      bf[nt] = *(bfrag8*)&Bs[wn + nt * 16 + lm][quad * 8];
#pragma unroll
    for (int mt = 0; mt < 4; ++mt)
#pragma unroll
      for (int nt = 0; nt < 4; ++nt)
        acc[mt][nt] = __builtin_amdgcn_mfma_f32_16x16x32_bf16(
            af[mt], bf[nt], acc[mt][nt], 0, 0, 0);
    __syncthreads();
  }
#pragma unroll
  for (int mt = 0; mt < 4; ++mt)
#pragma unroll
    for (int nt = 0; nt < 4; ++nt) {
      int col = bn * 128 + wn + nt * 16 + lm;
      float bv = bias[col];
#pragma unroll
      for (int r = 0; r < 4; ++r) {
        int row = bm * 128 + wm + mt * 16 + quad * 4 + r;
        C[(size_t)row * 512 + col] = acc[mt][nt][r] + bv;
      }
    }
}

// ---------------------------------------------------------------------------
// m[b,h,l] = max_s(q.k_sample) - sum_s(q.k_sample)/L
// ---------------------------------------------------------------------------
__global__ __launch_bounds__(256) void compute_m(
    const float* __restrict__ q, const float* __restrict__ k,
    const int* __restrict__ idxs, float* __restrict__ m) {
  int wave = threadIdx.x >> 6, lane = threadIdx.x & 63;
  int lq = lane >> 4, dq = lane & 15;
  int slot = (blockIdx.x * 4 + wave) * 4 + lq;  // (b,h,l) flat
  int l = slot & (Lq - 1);
  int bh = slot >> 11;
  int h = bh & (Hq - 1), b = bh >> 3;
  float4 qv = *(const float4*)&q[((size_t)b * Lq + l) * Dq + h * DKq + dq * 4];
  const float* kb = &k[(size_t)b * Lq * Dq + h * DKq + dq * 4];
  const int* ib = &idxs[l * Uq];
  float mx = -INFINITY, sm = 0.f;
#pragma unroll
  for (int s = 0; s < Uq; ++s) {
    int j = ib[s];
    float4 kv = *(const float4*)&kb[(size_t)j * Dq];
    float p = qv.x * kv.x + qv.y * kv.y + qv.z * kv.z + qv.w * kv.w;
    p += __shfl_xor(p, 1, 64);
    p += __shfl_xor(p, 2, 64);
    p += __shfl_xor(p, 4, 64);
    p += __shfl_xor(p, 8, 64);
    mx = fmaxf(mx, p);
    sm += p;
  }
  if (dq == 0) m[slot] = mx - sm * (1.0f / Lq);
}

// ---------------------------------------------------------------------------
// top-24 per (b,h), two-stage bitonic on packed keys.
// ---------------------------------------------------------------------------
__device__ inline void bitonic256_desc(u64* s, int tid) {
  for (int k = 2; k <= 256; k <<= 1) {
    for (int j = k >> 1; j > 0; j >>= 1) {
      int p = tid ^ j;
      u64 mine = s[tid], other = s[p];
      u64 mx = mine > other ? mine : other;
      u64 mn = mine > other ? other : mine;
      bool dir = (tid & k) == 0;   // descending block
      bool lower = tid < p;
      u64 res = dir ? (lower ? mx : mn) : (lower ? mn : mx);
      __syncthreads();
      s[tid] = res;
      __syncthreads();
    }
  }
}

__global__ __launch_bounds__(256) void topk_stage1(
    const float* __restrict__ m, u64* __restrict__ cand) {
  __shared__ u64 s[256];
  int bh = blockIdx.x >> 3;      // 0..31
  int ch = blockIdx.x & 7;       // chunk 0..7
  int tid = threadIdx.x;
  int gidx = ch * 256 + tid;
  float v = m[(size_t)bh * Lq + gidx];
  s[tid] = ((u64)fkey(v) << 32) | (u64)(Lq - 1 - gidx);
  __syncthreads();
  bitonic256_desc(s, tid);
  if (tid < Uq) cand[((size_t)bh * TKCH + ch) * Uq + tid] = s[tid];
}

__global__ __launch_bounds__(256) void topk_stage2(
    const u64* __restrict__ cand, int* __restrict__ mtop) {
  __shared__ u64 s[256];
  int bh = blockIdx.x;
  int tid = threadIdx.x;
  s[tid] = (tid < TKCH * Uq) ? cand[(size_t)bh * TKCH * Uq + tid] : 0ull;
  __syncthreads();
  bitonic256_desc(s, tid);
  if (tid < Uq) mtop[bh * Uq + tid] = Lq - 1 - (int)(s[tid] & 0xFFFFFFFFull);
}

// ---------------------------------------------------------------------------
// repl[b,h,l] = u if l == mtop[b,h,u] else -1 (fill + match, one kernel)
// ---------------------------------------------------------------------------
__global__ __launch_bounds__(256) void make_repl(
    const int* __restrict__ mtop, int* __restrict__ repl) {
  __shared__ int mt[Uq];
  int bh = blockIdx.x >> 3;
  int ch = blockIdx.x & 7;
  int tid = threadIdx.x;
  if (tid < Uq) mt[tid] = mtop[bh * Uq + tid];
  __syncthreads();
  int l = ch * 256 + tid;
  int u = -1;
#pragma unroll
  for (int s = 0; s < Uq; ++s)
    if (mt[s] == l) u = s;
  repl[(size_t)bh * Lq + l] = u;
}

// ---------------------------------------------------------------------------
// scores[bh][u][j] = (q[b,i0[u],h,:] . k[b,j,h,:]) / sqrt(D)
// ---------------------------------------------------------------------------
#define JT 256
#define JS 64

__global__ __launch_bounds__(256) void scores_kernel(
    const float* __restrict__ q, const float* __restrict__ k,
    const int* __restrict__ mtop, float* __restrict__ scg) {
  __shared__ float qs[Uq][DKq + 1];
  __shared__ float ks[JS][DKq + 1];
  __shared__ int i0s[Uq];
  int bh = blockIdx.y;
  int jt = blockIdx.x;
  int h = bh & (Hq - 1);
  int b = bh >> 3;
  int tid = threadIdx.x;
  if (tid < Uq) i0s[tid] = mtop[bh * Uq + tid];
  __syncthreads();
  for (int s = tid; s < Uq * 16; s += 256) {
    int u = s >> 4, qd = (s & 15) * 4;
    float4 t = *(const float4*)&q[((size_t)b * Lq + i0s[u]) * Dq + h * DKq + qd];
    qs[u][qd] = t.x; qs[u][qd + 1] = t.y; qs[u][qd + 2] = t.z; qs[u][qd + 3] = t.w;
  }
  int jp = tid & 31;
  int ug = tid >> 5;
  const float scale = 0.044194173824159216f;  // 1/sqrt(512)
  for (int sub = 0; sub < JT / JS; ++sub) {
    int jbase = jt * JT + sub * JS;
    __syncthreads();
    for (int s = tid; s < JS * 16; s += 256) {
      int j = s >> 4, qd = (s & 15) * 4;
      float4 t = *(const float4*)&k[((size_t)b * Lq + jbase + j) * Dq + h * DKq + qd];
      ks[j][qd] = t.x; ks[j][qd + 1] = t.y; ks[j][qd + 2] = t.z; ks[j][qd + 3] = t.w;
    }
    __syncthreads();
    float acc[3][2] = {};
    int j0 = jp * 2, j1 = j0 + 1;
#pragma unroll 8
    for (int d = 0; d < DKq; ++d) {
      float k0 = ks[j0][d], k1 = ks[j1][d];
#pragma unroll
      for (int uu = 0; uu < 3; ++uu) {
        float qv = qs[ug * 3 + uu][d];
        acc[uu][0] += qv * k0;
        acc[uu][1] += qv * k1;
      }
    }
#pragma unroll
    for (int uu = 0; uu < 3; ++uu) {
      int u = ug * 3 + uu;
      scg[((size_t)(bh * Uq + u)) * Lq + jbase + j0] = acc[uu][0] * scale;
      scg[((size_t)(bh * Uq + u)) * Lq + jbase + j1] = acc[uu][1] * scale;
    }
  }
}

// ---------------------------------------------------------------------------
// softmax+PV, split over j-chunks of 256 for TLP.
// ---------------------------------------------------------------------------
__global__ __launch_bounds__(256) void softmax_pv_partial(
    const float* __restrict__ scg, const float* __restrict__ v,
    const int* __restrict__ mtop, float* __restrict__ pmax,
    float* __restrict__ psum, float* __restrict__ pvp) {
  int blk = blockIdx.y;  // bh*U + u
  int jc = blockIdx.x;
  int bh = blk / Uq;
  int h = bh & (Hq - 1);
  int b = bh >> 3;
  int n = mtop[blk] + 1;   // causal bound
  int j0 = jc * JCH;
  if (j0 >= n) return;
  int cnt = min(JCH, n - j0);
  int tid = threadIdx.x, wave = tid >> 6, lane = tid & 63;
  __shared__ float es[JCH];
  __shared__ float red[4][DKq];
  __shared__ float rr[4];

  const float* row = &scg[(size_t)blk * Lq + j0];
  float mx = (tid < cnt) ? row[tid] : -INFINITY;
#pragma unroll
  for (int off = 32; off; off >>= 1) mx = fmaxf(mx, __shfl_xor(mx, off, 64));
  if (lane == 0) rr[wave] = mx;
  __syncthreads();
  mx = fmaxf(fmaxf(rr[0], rr[1]), fmaxf(rr[2], rr[3]));
  __syncthreads();

  float e = (tid < cnt) ? __expf(row[tid] - mx) : 0.f;
  es[tid] = e;
  float sm = e;
#pragma unroll
  for (int off = 32; off; off >>= 1) sm += __shfl_xor(sm, off, 64);
  if (lane == 0) rr[wave] = sm;
  __syncthreads();

  float acc = 0.f;
  const float* vb = &v[((size_t)b * Lq + j0) * Dq + h * DKq + lane];
  int jlo = wave * 64;
  int jhi = min(jlo + 64, cnt);
#pragma unroll 4
  for (int j = jlo; j < jhi; ++j) acc += es[j] * vb[(size_t)j * Dq];
  red[wave][lane] = acc;
  __syncthreads();
  if (wave == 0) {
    if (lane == 0) {
      pmax[blk * NCH + jc] = mx;
      psum[blk * NCH + jc] = rr[0] + rr[1] + rr[2] + rr[3];
    }
    pvp[((size_t)blk * NCH + jc) * DKq + lane] =
        red[0][lane] + red[1][lane] + red[2][lane] + red[3][lane];
  }
}

__global__ __launch_bounds__(256) void softmax_pv_combine(
    const float* __restrict__ pmax, const float* __restrict__ psum,
    const float* __restrict__ pvp, const int* __restrict__ mtop,
    float* __restrict__ attnv) {
  int blk = blockIdx.x * 4 + (threadIdx.x >> 6);  // bh*U + u
  int lane = threadIdx.x & 63;
  int n = mtop[blk] + 1;
  int nc = (n + JCH - 1) / JCH;
  float gmax = -INFINITY;
  for (int c = 0; c < nc; ++c) gmax = fmaxf(gmax, pmax[blk * NCH + c]);
  float tot = 0.f, acc = 0.f;
  for (int c = 0; c < nc; ++c) {
    float w = __expf(pmax[blk * NCH + c] - gmax);
    tot += psum[blk * NCH + c] * w;
    acc += pvp[((size_t)blk * NCH + c) * DKq + lane] * w;
  }
  attnv[(size_t)blk * DKq + lane] = acc / tot;
}

// ---------------------------------------------------------------------------
// cumsum over L: tile sums, then build_context with inline exclusive
// prefix (parallel L2 loads) + scatter + direct bf16 output.
// ---------------------------------------------------------------------------
__global__ __launch_bounds__(128) void tile_sum(const float* __restrict__ v,
                                                float* __restrict__ tsum) {
  int blk = blockIdx.x;  // b*NTILE + tile
  int tile = blk & (NTILE - 1);
  int b = blk >> 7;
  int d4 = threadIdx.x;  // 0..127 (float4 column slice)
  float4 s = {0.f, 0.f, 0.f, 0.f};
  const float* base = &v[((size_t)b * Lq + tile * TSCAN) * Dq + d4 * 4];
#pragma unroll
  for (int r = 0; r < TSCAN; ++r) {
    float4 x = *(const float4*)&base[(size_t)r * Dq];
    s.x += x.x; s.y += x.y; s.z += x.z; s.w += x.w;
  }
  *(float4*)&tsum[((size_t)b * NTILE + tile) * Dq + d4 * 4] = s;
}

__global__ __launch_bounds__(128) void build_context(
    const float* __restrict__ v, const float* __restrict__ tsum,
    const int* __restrict__ repl, const float* __restrict__ attnv,
    ushort_t* __restrict__ ctxh) {
  int blk = blockIdx.x;  // b*NTILE + tile
  int tile = blk & (NTILE - 1);
  int b = blk >> 7;
  int d4 = threadIdx.x;          // float4 column slice
  int h = d4 >> 4;               // (d4*4)>>6
  // exclusive prefix over preceding tile sums (independent L2 loads)
  float4 run = {0.f, 0.f, 0.f, 0.f};
  const float* tb = &tsum[(size_t)b * NTILE * Dq + d4 * 4];
  for (int i = 0; i < tile; ++i) {
    float4 t = *(const float4*)&tb[(size_t)i * Dq];
    run.x += t.x; run.y += t.y; run.z += t.z; run.w += t.w;
  }
  const int* replb = &repl[(size_t)(b * Hq + h) * Lq + tile * TSCAN];
  const float* vb = &v[((size_t)b * Lq + tile * TSCAN) * Dq + d4 * 4];
  ushort_t* cb = &ctxh[((size_t)b * Lq + tile * TSCAN) * Dq + d4 * 4];
  const float* ab = &attnv[(size_t)(b * Hq + h) * Uq * DKq + (d4 & 15) * 4];
#pragma unroll
  for (int r = 0; r < TSCAN; ++r) {
    float4 x = *(const float4*)&vb[(size_t)r * Dq];
    run.x += x.x; run.y += x.y; run.z += x.z; run.w += x.w;
    int u = replb[r];
    float4 val = run;
    if (u >= 0) val = *(const float4*)&ab[(size_t)u * DKq];
    ushort4 o = {bf16_rne(val.x), bf16_rne(val.y), bf16_rne(val.z),
                 bf16_rne(val.w)};
    *(ushort4*)&cb[(size_t)r * Dq] = o;
  }
}

// ---------------------------------------------------------------------------
extern "C" void kernel_launch(void* const* d_in, const int* in_sizes, int n_in,
                              void* d_out, int out_size, void* d_ws,
                              size_t ws_size, hipStream_t stream) {
  const float* queries = (const float*)d_in[0];
  const float* keys    = (const float*)d_in[1];
  const float* values  = (const float*)d_in[2];
  const int*   idxs    = (const int*)d_in[3];
  const float* Wq = (const float*)d_in[4];
  const float* bq = (const float*)d_in[5];
  const float* Wk = (const float*)d_in[6];
  const float* bk = (const float*)d_in[7];
  const float* Wv = (const float*)d_in[8];
  const float* bv = (const float*)d_in[9];
  const float* Wo = (const float*)d_in[10];
  const float* bo = (const float*)d_in[11];
  float* out = (float*)d_out;

  const size_t BLD = (size_t)Bq * Lq * Dq;  // 4,194,304
  char* w = (char*)d_ws;
  float* q    = (float*)w; w += BLD * 4;
  float* k    = (float*)w; w += BLD * 4;
  float* v    = (float*)w; w += BLD * 4;
  float* scg  = (float*)w; w += (size_t)Bq * Hq * Uq * Lq * 4;  // 6.3 MB
  float* m    = (float*)w; w += (size_t)Bq * Hq * Lq * 4;
  float* attnv= (float*)w; w += (size_t)Bq * Hq * Uq * DKq * 4;
  float* tsum = (float*)w; w += (size_t)Bq * NTILE * Dq * 4;
  int* mtop   = (int*)w;   w += Bq * Hq * Uq * 4;
  int* repl   = (int*)w;   w += (size_t)Bq * Hq * Lq * 4;
  float* pmax = (float*)w; w += (size_t)Bq * Hq * Uq * NCH * 4;
  float* psum = (float*)w; w += (size_t)Bq * Hq * Uq * NCH * 4;
  float* pvp  = (float*)w; w += (size_t)Bq * Hq * Uq * NCH * DKq * 4;
  u64* cand   = (u64*)w;   w += (size_t)Bq * Hq * TKCH * Uq * 8;
  ushort_t* ctxh = (ushort_t*)w; w += BLD * 2;  // bf16 context
  ushort_t* Aqh = (ushort_t*)w; w += BLD * 2;   // pre-cast activations
  ushort_t* Aql = (ushort_t*)w; w += BLD * 2;
  ushort_t* Akh = (ushort_t*)w; w += BLD * 2;
  ushort_t* Akl = (ushort_t*)w; w += BLD * 2;
  ushort_t* Avh = (ushort_t*)w; w += BLD * 2;
  const size_t WSZ = 512 * 512;
  ushort_t* Wqh = (ushort_t*)w; w += WSZ * 2;
  ushort_t* Wql = (ushort_t*)w; w += WSZ * 2;
  ushort_t* Wkh = (ushort_t*)w; w += WSZ * 2;
  ushort_t* Wkl = (ushort_t*)w; w += WSZ * 2;
  ushort_t* Wvh = (ushort_t*)w; w += WSZ * 2;
  ushort_t* Woh = (ushort_t*)w; w += WSZ * 2;

  // weights: transpose + hi/lo cast, one launch
  {
    dim3 tgrid(16, 16, 4);
    transpose_cast4<<<tgrid, 256, 0, stream>>>(Wq, Wk, Wv, Wo, Wqh, Wql, Wkh,
                                               Wkl, Wvh, Woh);
  }

  // pre-cast activations (Q,K hi/lo; V hi)
  const int CAST_B = (int)(BLD / 4 / 256);  // 4096 blocks
  cast_hilo<<<CAST_B, 256, 0, stream>>>(queries, Aqh, Aql, (int)(BLD / 4));
  cast_hilo<<<CAST_B, 256, 0, stream>>>(keys, Akh, Akl, (int)(BLD / 4));
  cast_hi<<<CAST_B, 256, 0, stream>>>(values, Avh, (int)(BLD / 4));

  // fused Q/K/V projections (128x128 tiles, async LDS staging)
  {
    dim3 ggrid(64, 4, 3);  // M=8192/128, N=512/128, z = Q/K/V
    gemm_qkv<<<ggrid, 256, 0, stream>>>(Aqh, Aql, Akh, Akl, Avh, Wqh, Wql,
                                        Wkh, Wkl, Wvh, bq, bk, bv, q, k, v);
  }

  // sparsity metric + top-k (two-stage bitonic) + replacement table
  compute_m<<<(Bq * Hq * Lq) / 16, 256, 0, stream>>>(q, k, idxs, m);
  topk_stage1<<<Bq * Hq * TKCH, 256, 0, stream>>>(m, cand);
  topk_stage2<<<Bq * Hq, 256, 0, stream>>>(cand, mtop);
  make_repl<<<Bq * Hq * 8, 256, 0, stream>>>(mtop, repl);

  // attention on the top-24 rows
  {
    dim3 sgrid(Lq / JT, Bq * Hq);  // (8, 32)
    scores_kernel<<<sgrid, 256, 0, stream>>>(q, k, mtop, scg);
  }
  {
    dim3 pgrid(NCH, Bq * Hq * Uq);  // (8, 768)
    softmax_pv_partial<<<pgrid, 256, 0, stream>>>(scg, v, mtop, pmax, psum, pvp);
    softmax_pv_combine<<<Bq * Hq * Uq / 4, 256, 0, stream>>>(pmax, psum, pvp,
                                                             mtop, attnv);
  }

  // cumsum context + scatter, bf16 output (inline prefix — no tile_prefix)
  tile_sum<<<Bq * NTILE, 128, 0, stream>>>(v, tsum);
  build_context<<<Bq * NTILE, 128, 0, stream>>>(v, tsum, repl, attnv, ctxh);

  // output projection (plain bf16, 128x128 tiles, async LDS staging)
  {
    dim3 ggrid(64, 4);
    gemm_bf16<<<ggrid, 256, 0, stream>>>(ctxh, Woh, bo, out);
  }
}

// Round 10
// 297.297 us; speedup vs baseline: 1.0604x; 1.0081x over previous
//
#include <hip/hip_runtime.h>
#include <hip/hip_bf16.h>
#include <math.h>

#define Bq 4
#define Lq 2048
#define Dq 512
#define Hq 8
#define DKq 64
#define Uq 24
#define TSCAN 16
#define NTILE (Lq / TSCAN)   // 128
#define JCH 256              // softmax j-chunk
#define NCH (Lq / JCH)       // 8
#define TKCH 8               // top-k chunks per bh

typedef unsigned short ushort_t;
typedef unsigned long long u64;
typedef __attribute__((ext_vector_type(8))) short bfrag8;   // 8 bf16 (4 VGPRs)
typedef __attribute__((ext_vector_type(4))) float facc4;    // MFMA accumulator

__device__ inline ushort_t bf16_rne(float f) {
  unsigned u = __float_as_uint(f);
  u += 0x7FFF + ((u >> 16) & 1);
  return (ushort_t)(u >> 16);
}
__device__ inline float bf16f(ushort_t h) {
  return __uint_as_float(((unsigned)h) << 16);
}
// monotone float -> uint map (no NaNs in inputs)
__device__ inline unsigned fkey(float f) {
  unsigned u = __float_as_uint(f);
  return (u & 0x80000000u) ? ~u : (u | 0x80000000u);
}
// async global->LDS, 16B per lane (lds dest = wave base + lane*16)
__device__ __forceinline__ void gl2lds16(const void* g, void* l) {
  __builtin_amdgcn_global_load_lds(
      (const __attribute__((address_space(1))) unsigned*)g,
      (__attribute__((address_space(3))) unsigned*)l, 16, 0, 0);
}

// ---------------------------------------------------------------------------
// activations: one launch. y=0: q->hi/lo, y=1: k->hi/lo, y=2: v->hi
// ---------------------------------------------------------------------------
__global__ __launch_bounds__(256) void cast_all(
    const float* __restrict__ xq, const float* __restrict__ xk,
    const float* __restrict__ xv, ushort_t* __restrict__ qh,
    ushort_t* __restrict__ ql, ushort_t* __restrict__ kh,
    ushort_t* __restrict__ kl, ushort_t* __restrict__ vh) {
  int z = blockIdx.y;
  const float* x = z == 0 ? xq : (z == 1 ? xk : xv);
  ushort_t* hi = z == 0 ? qh : (z == 1 ? kh : vh);
  ushort_t* lo = z == 0 ? ql : kl;  // unused for z==2
  int t = blockIdx.x * 256 + threadIdx.x;
  float4 v = *(const float4*)&x[(size_t)t * 4];
  ushort_t h0 = bf16_rne(v.x), h1 = bf16_rne(v.y), h2 = bf16_rne(v.z),
           h3 = bf16_rne(v.w);
  ushort4 hh = {h0, h1, h2, h3};
  *(ushort4*)&hi[(size_t)t * 4] = hh;
  if (z < 2) {
    ushort4 ll = {bf16_rne(v.x - bf16f(h0)), bf16_rne(v.y - bf16f(h1)),
                  bf16_rne(v.z - bf16f(h2)), bf16_rne(v.w - bf16f(h3))};
    *(ushort4*)&lo[(size_t)t * 4] = ll;
  }
}

// ---------------------------------------------------------------------------
// All 4 weights: fp32 [k][n] -> transposed bf16 hi/lo [n][k] (one launch)
// ---------------------------------------------------------------------------
__global__ __launch_bounds__(256) void transpose_cast4(
    const float* __restrict__ W0, const float* __restrict__ W1,
    const float* __restrict__ W2, const float* __restrict__ W3,
    ushort_t* __restrict__ T0h, ushort_t* __restrict__ T0l,
    ushort_t* __restrict__ T1h, ushort_t* __restrict__ T1l,
    ushort_t* __restrict__ T2h, ushort_t* __restrict__ T3h) {
  __shared__ float tile[32][33];
  int z = blockIdx.z;
  const float* W = z == 0 ? W0 : (z == 1 ? W1 : (z == 2 ? W2 : W3));
  ushort_t* Th = z == 0 ? T0h : (z == 1 ? T1h : (z == 2 ? T2h : T3h));
  ushort_t* Tl = z == 0 ? T0l : (z == 1 ? T1l : nullptr);
  int k0 = blockIdx.x * 32, n0 = blockIdx.y * 32;
  int tx = threadIdx.x & 31, ty = threadIdx.x >> 5;  // ty 0..7
  for (int r = ty; r < 32; r += 8)
    tile[tx][r] = W[(size_t)(k0 + r) * 512 + n0 + tx];
  __syncthreads();
  for (int r = ty; r < 32; r += 8) {
    float v = tile[r][tx];
    ushort_t h = bf16_rne(v);
    Th[(size_t)(n0 + r) * 512 + k0 + tx] = h;
    if (Tl) Tl[(size_t)(n0 + r) * 512 + k0 + tx] = bf16_rne(v - bf16f(h));
  }
}

// ---------------------------------------------------------------------------
// Fused Q/K/V projection GEMM, 128x128 tile, 4 waves x (64x64).
// z=0: Q (split-bf16), z=1: K (split), z=2: V (plain hi).
// Pre-cast bf16 inputs; async global_load_lds staging; m97 [128][32] layout.
// ---------------------------------------------------------------------------
__global__ __launch_bounds__(256) void gemm_qkv(
    const ushort_t* __restrict__ Aqh, const ushort_t* __restrict__ Aql,
    const ushort_t* __restrict__ Akh, const ushort_t* __restrict__ Akl,
    const ushort_t* __restrict__ Avh,
    const ushort_t* __restrict__ Wqh, const ushort_t* __restrict__ Wql,
    const ushort_t* __restrict__ Wkh, const ushort_t* __restrict__ Wkl,
    const ushort_t* __restrict__ Wvh,
    const float* __restrict__ bq, const float* __restrict__ bk,
    const float* __restrict__ bv,
    float* __restrict__ qo, float* __restrict__ ko, float* __restrict__ vo) {
  __shared__ ushort_t Ash[128][32], Asl[128][32];  // 8 KB each
  __shared__ ushort_t Bsh[128][32], Bsl[128][32];
  int which = blockIdx.z;
  const ushort_t* Ah = which == 0 ? Aqh : (which == 1 ? Akh : Avh);
  const ushort_t* Al = which == 0 ? Aql : Akl;  // unused for V
  const ushort_t* Bh = which == 0 ? Wqh : (which == 1 ? Wkh : Wvh);
  const ushort_t* Bl = which == 0 ? Wql : Wkl;
  const float* bias = which == 0 ? bq : (which == 1 ? bk : bv);
  float* C = which == 0 ? qo : (which == 1 ? ko : vo);
  const bool split = which < 2;

  int bm = blockIdx.x, bn = blockIdx.y;
  int tid = threadIdx.x;
  int wave = tid >> 6, lane = tid & 63;
  int wm = (wave & 1) * 64, wn = (wave >> 1) * 64;
  int quad = lane >> 4, lm = lane & 15;
  int srow = tid >> 2, skq = (tid & 3) * 8;   // staging slot (s = tid, tid+256)
  facc4 acc[4][4] = {};

  for (int k0 = 0; k0 < 512; k0 += 32) {
    // async staging: LDS offset = s*16B per lane (contiguous in lane order)
#pragma unroll
    for (int p = 0; p < 2; ++p) {
      int row = srow + p * 64;
      size_t ga = (size_t)(bm * 128 + row) * 512 + k0 + skq;
      size_t gb = (size_t)(bn * 128 + row) * 512 + k0 + skq;
      gl2lds16(&Ah[ga], &Ash[row][skq]);
      gl2lds16(&Bh[gb], &Bsh[row][skq]);
      if (split) {
        gl2lds16(&Al[ga], &Asl[row][skq]);
        gl2lds16(&Bl[gb], &Bsl[row][skq]);
      }
    }
    __syncthreads();
    bfrag8 afh[4], afl[4], bfh[4], bfl[4];
#pragma unroll
    for (int mt = 0; mt < 4; ++mt) {
      afh[mt] = *(bfrag8*)&Ash[wm + mt * 16 + lm][quad * 8];
      if (split) afl[mt] = *(bfrag8*)&Asl[wm + mt * 16 + lm][quad * 8];
    }
#pragma unroll
    for (int nt = 0; nt < 4; ++nt) {
      bfh[nt] = *(bfrag8*)&Bsh[wn + nt * 16 + lm][quad * 8];
      if (split) bfl[nt] = *(bfrag8*)&Bsl[wn + nt * 16 + lm][quad * 8];
    }
#pragma unroll
    for (int mt = 0; mt < 4; ++mt)
#pragma unroll
      for (int nt = 0; nt < 4; ++nt) {
        facc4 a = acc[mt][nt];
        a = __builtin_amdgcn_mfma_f32_16x16x32_bf16(afh[mt], bfh[nt], a, 0, 0, 0);
        if (split) {
          a = __builtin_amdgcn_mfma_f32_16x16x32_bf16(afl[mt], bfh[nt], a, 0, 0, 0);
          a = __builtin_amdgcn_mfma_f32_16x16x32_bf16(afh[mt], bfl[nt], a, 0, 0, 0);
        }
        acc[mt][nt] = a;
      }
    __syncthreads();
  }
#pragma unroll
  for (int mt = 0; mt < 4; ++mt)
#pragma unroll
    for (int nt = 0; nt < 4; ++nt) {
      int col = bn * 128 + wn + nt * 16 + lm;
      float bv2 = bias[col];
#pragma unroll
      for (int r = 0; r < 4; ++r) {
        int row = bm * 128 + wm + mt * 16 + quad * 4 + r;
        C[(size_t)row * 512 + col] = acc[mt][nt][r] + bv2;
      }
    }
}

// ---------------------------------------------------------------------------
// bf16 MFMA GEMM (hi only, bf16 A): out projection, 128x128 tile, async stage
// ---------------------------------------------------------------------------
__global__ __launch_bounds__(256) void gemm_bf16(
    const ushort_t* __restrict__ A, const ushort_t* __restrict__ Bt,
    const float* __restrict__ bias, float* __restrict__ C) {
  __shared__ ushort_t As[128][32];
  __shared__ ushort_t Bs[128][32];
  int bm = blockIdx.x, bn = blockIdx.y;
  int tid = threadIdx.x;
  int wave = tid >> 6, lane = tid & 63;
  int wm = (wave & 1) * 64, wn = (wave >> 1) * 64;
  int quad = lane >> 4, lm = lane & 15;
  int srow = tid >> 2, skq = (tid & 3) * 8;
  facc4 acc[4][4] = {};

  for (int k0 = 0; k0 < 512; k0 += 32) {
#pragma unroll
    for (int p = 0; p < 2; ++p) {
      int row = srow + p * 64;
      gl2lds16(&A[(size_t)(bm * 128 + row) * 512 + k0 + skq], &As[row][skq]);
      gl2lds16(&Bt[(size_t)(bn * 128 + row) * 512 + k0 + skq], &Bs[row][skq]);
    }
    __syncthreads();
    bfrag8 af[4], bf[4];
#pragma unroll
    for (int mt = 0; mt < 4; ++mt)
      af[mt] = *(bfrag8*)&As[wm + mt * 16 + lm][quad * 8];
#pragma unroll
    for (int nt = 0; nt < 4; ++nt)
      bf[nt] = *(bfrag8*)&Bs[wn + nt * 16 + lm][quad * 8];
#pragma unroll
    for (int mt = 0; mt < 4; ++mt)
#pragma unroll
      for (int nt = 0; nt < 4; ++nt)
        acc[mt][nt] = __builtin_amdgcn_mfma_f32_16x16x32_bf16(
            af[mt], bf[nt], acc[mt][nt], 0, 0, 0);
    __syncthreads();
  }
#pragma unroll
  for (int mt = 0; mt < 4; ++mt)
#pragma unroll
    for (int nt = 0; nt < 4; ++nt) {
      int col = bn * 128 + wn + nt * 16 + lm;
      float bv = bias[col];
#pragma unroll
      for (int r = 0; r < 4; ++r) {
        int row = bm * 128 + wm + mt * 16 + quad * 4 + r;
        C[(size_t)row * 512 + col] = acc[mt][nt][r] + bv;
      }
    }
}

// ---------------------------------------------------------------------------
// m[b,h,l] = max_s(q.k_sample) - sum_s(q.k_sample)/L
// ---------------------------------------------------------------------------
__global__ __launch_bounds__(256) void compute_m(
    const float* __restrict__ q, const float* __restrict__ k,
    const int* __restrict__ idxs, float* __restrict__ m) {
  int wave = threadIdx.x >> 6, lane = threadIdx.x & 63;
  int lq = lane >> 4, dq = lane & 15;
  int slot = (blockIdx.x * 4 + wave) * 4 + lq;  // (b,h,l) flat
  int l = slot & (Lq - 1);
  int bh = slot >> 11;
  int h = bh & (Hq - 1), b = bh >> 3;
  float4 qv = *(const float4*)&q[((size_t)b * Lq + l) * Dq + h * DKq + dq * 4];
  const float* kb = &k[(size_t)b * Lq * Dq + h * DKq + dq * 4];
  const int* ib = &idxs[l * Uq];
  float mx = -INFINITY, sm = 0.f;
#pragma unroll
  for (int s = 0; s < Uq; ++s) {
    int j = ib[s];
    float4 kv = *(const float4*)&kb[(size_t)j * Dq];
    float p = qv.x * kv.x + qv.y * kv.y + qv.z * kv.z + qv.w * kv.w;
    p += __shfl_xor(p, 1, 64);
    p += __shfl_xor(p, 2, 64);
    p += __shfl_xor(p, 4, 64);
    p += __shfl_xor(p, 8, 64);
    mx = fmaxf(mx, p);
    sm += p;
  }
  if (dq == 0) m[slot] = mx - sm * (1.0f / Lq);
}

// ---------------------------------------------------------------------------
// top-24 per (b,h), two-stage bitonic on packed keys.
// stage2 also builds repl[] (indices already in LDS).
// ---------------------------------------------------------------------------
__device__ inline void bitonic256_desc(u64* s, int tid) {
  for (int k = 2; k <= 256; k <<= 1) {
    for (int j = k >> 1; j > 0; j >>= 1) {
      int p = tid ^ j;
      u64 mine = s[tid], other = s[p];
      u64 mx = mine > other ? mine : other;
      u64 mn = mine > other ? other : mine;
      bool dir = (tid & k) == 0;   // descending block
      bool lower = tid < p;
      u64 res = dir ? (lower ? mx : mn) : (lower ? mn : mx);
      __syncthreads();
      s[tid] = res;
      __syncthreads();
    }
  }
}

__global__ __launch_bounds__(256) void topk_stage1(
    const float* __restrict__ m, u64* __restrict__ cand) {
  __shared__ u64 s[256];
  int bh = blockIdx.x >> 3;      // 0..31
  int ch = blockIdx.x & 7;       // chunk 0..7
  int tid = threadIdx.x;
  int gidx = ch * 256 + tid;
  float v = m[(size_t)bh * Lq + gidx];
  s[tid] = ((u64)fkey(v) << 32) | (u64)(Lq - 1 - gidx);
  __syncthreads();
  bitonic256_desc(s, tid);
  if (tid < Uq) cand[((size_t)bh * TKCH + ch) * Uq + tid] = s[tid];
}

__global__ __launch_bounds__(256) void topk_stage2(
    const u64* __restrict__ cand, int* __restrict__ mtop,
    int* __restrict__ repl) {
  __shared__ u64 s[256];
  __shared__ int mt[Uq];
  int bh = blockIdx.x;
  int tid = threadIdx.x;
  s[tid] = (tid < TKCH * Uq) ? cand[(size_t)bh * TKCH * Uq + tid] : 0ull;
  __syncthreads();
  bitonic256_desc(s, tid);
  if (tid < Uq) {
    int idx = Lq - 1 - (int)(s[tid] & 0xFFFFFFFFull);
    mtop[bh * Uq + tid] = idx;
    mt[tid] = idx;
  }
  __syncthreads();
  // replacement table: 8 l's per thread, compare vs 24 LDS entries
  for (int l = tid; l < Lq; l += 256) {
    int u = -1;
#pragma unroll
    for (int t = 0; t < Uq; ++t)
      if (mt[t] == l) u = t;
    repl[(size_t)bh * Lq + l] = u;
  }
}

// ---------------------------------------------------------------------------
// scores[bh][u][j] = (q[b,i0[u],h,:] . k[b,j,h,:]) / sqrt(D)
// ---------------------------------------------------------------------------
#define JT 256
#define JS 64

__global__ __launch_bounds__(256) void scores_kernel(
    const float* __restrict__ q, const float* __restrict__ k,
    const int* __restrict__ mtop, float* __restrict__ scg) {
  __shared__ float qs[Uq][DKq + 1];
  __shared__ float ks[JS][DKq + 1];
  __shared__ int i0s[Uq];
  int bh = blockIdx.y;
  int jt = blockIdx.x;
  int h = bh & (Hq - 1);
  int b = bh >> 3;
  int tid = threadIdx.x;
  if (tid < Uq) i0s[tid] = mtop[bh * Uq + tid];
  __syncthreads();
  for (int s = tid; s < Uq * 16; s += 256) {
    int u = s >> 4, qd = (s & 15) * 4;
    float4 t = *(const float4*)&q[((size_t)b * Lq + i0s[u]) * Dq + h * DKq + qd];
    qs[u][qd] = t.x; qs[u][qd + 1] = t.y; qs[u][qd + 2] = t.z; qs[u][qd + 3] = t.w;
  }
  int jp = tid & 31;
  int ug = tid >> 5;
  const float scale = 0.044194173824159216f;  // 1/sqrt(512)
  for (int sub = 0; sub < JT / JS; ++sub) {
    int jbase = jt * JT + sub * JS;
    __syncthreads();
    for (int s = tid; s < JS * 16; s += 256) {
      int j = s >> 4, qd = (s & 15) * 4;
      float4 t = *(const float4*)&k[((size_t)b * Lq + jbase + j) * Dq + h * DKq + qd];
      ks[j][qd] = t.x; ks[j][qd + 1] = t.y; ks[j][qd + 2] = t.z; ks[j][qd + 3] = t.w;
    }
    __syncthreads();
    float acc[3][2] = {};
    int j0 = jp * 2, j1 = j0 + 1;
#pragma unroll 8
    for (int d = 0; d < DKq; ++d) {
      float k0 = ks[j0][d], k1 = ks[j1][d];
#pragma unroll
      for (int uu = 0; uu < 3; ++uu) {
        float qv = qs[ug * 3 + uu][d];
        acc[uu][0] += qv * k0;
        acc[uu][1] += qv * k1;
      }
    }
#pragma unroll
    for (int uu = 0; uu < 3; ++uu) {
      int u = ug * 3 + uu;
      scg[((size_t)(bh * Uq + u)) * Lq + jbase + j0] = acc[uu][0] * scale;
      scg[((size_t)(bh * Uq + u)) * Lq + jbase + j1] = acc[uu][1] * scale;
    }
  }
}

// ---------------------------------------------------------------------------
// softmax+PV, split over j-chunks of 256 for TLP.
// ---------------------------------------------------------------------------
__global__ __launch_bounds__(256) void softmax_pv_partial(
    const float* __restrict__ scg, const float* __restrict__ v,
    const int* __restrict__ mtop, float* __restrict__ pmax,
    float* __restrict__ psum, float* __restrict__ pvp) {
  int blk = blockIdx.y;  // bh*U + u
  int jc = blockIdx.x;
  int bh = blk / Uq;
  int h = bh & (Hq - 1);
  int b = bh >> 3;
  int n = mtop[blk] + 1;   // causal bound
  int j0 = jc * JCH;
  if (j0 >= n) return;
  int cnt = min(JCH, n - j0);
  int tid = threadIdx.x, wave = tid >> 6, lane = tid & 63;
  __shared__ float es[JCH];
  __shared__ float red[4][DKq];
  __shared__ float rr[4];

  const float* row = &scg[(size_t)blk * Lq + j0];
  float mx = (tid < cnt) ? row[tid] : -INFINITY;
#pragma unroll
  for (int off = 32; off; off >>= 1) mx = fmaxf(mx, __shfl_xor(mx, off, 64));
  if (lane == 0) rr[wave] = mx;
  __syncthreads();
  mx = fmaxf(fmaxf(rr[0], rr[1]), fmaxf(rr[2], rr[3]));
  __syncthreads();

  float e = (tid < cnt) ? __expf(row[tid] - mx) : 0.f;
  es[tid] = e;
  float sm = e;
#pragma unroll
  for (int off = 32; off; off >>= 1) sm += __shfl_xor(sm, off, 64);
  if (lane == 0) rr[wave] = sm;
  __syncthreads();

  float acc = 0.f;
  const float* vb = &v[((size_t)b * Lq + j0) * Dq + h * DKq + lane];
  int jlo = wave * 64;
  int jhi = min(jlo + 64, cnt);
#pragma unroll 4
  for (int j = jlo; j < jhi; ++j) acc += es[j] * vb[(size_t)j * Dq];
  red[wave][lane] = acc;
  __syncthreads();
  if (wave == 0) {
    if (lane == 0) {
      pmax[blk * NCH + jc] = mx;
      psum[blk * NCH + jc] = rr[0] + rr[1] + rr[2] + rr[3];
    }
    pvp[((size_t)blk * NCH + jc) * DKq + lane] =
        red[0][lane] + red[1][lane] + red[2][lane] + red[3][lane];
  }
}

__global__ __launch_bounds__(256) void softmax_pv_combine(
    const float* __restrict__ pmax, const float* __restrict__ psum,
    const float* __restrict__ pvp, const int* __restrict__ mtop,
    float* __restrict__ attnv) {
  int blk = blockIdx.x * 4 + (threadIdx.x >> 6);  // bh*U + u
  int lane = threadIdx.x & 63;
  int n = mtop[blk] + 1;
  int nc = (n + JCH - 1) / JCH;
  float gmax = -INFINITY;
  for (int c = 0; c < nc; ++c) gmax = fmaxf(gmax, pmax[blk * NCH + c]);
  float tot = 0.f, acc = 0.f;
  for (int c = 0; c < nc; ++c) {
    float w = __expf(pmax[blk * NCH + c] - gmax);
    tot += psum[blk * NCH + c] * w;
    acc += pvp[((size_t)blk * NCH + c) * DKq + lane] * w;
  }
  attnv[(size_t)blk * DKq + lane] = acc / tot;
}

// ---------------------------------------------------------------------------
// cumsum over L: tile sums, then build_context with inline exclusive
// prefix (parallel L2 loads) + scatter + direct bf16 output.
// ---------------------------------------------------------------------------
__global__ __launch_bounds__(128) void tile_sum(const float* __restrict__ v,
                                                float* __restrict__ tsum) {
  int blk = blockIdx.x;  // b*NTILE + tile
  int tile = blk & (NTILE - 1);
  int b = blk >> 7;
  int d4 = threadIdx.x;  // 0..127 (float4 column slice)
  float4 s = {0.f, 0.f, 0.f, 0.f};
  const float* base = &v[((size_t)b * Lq + tile * TSCAN) * Dq + d4 * 4];
#pragma unroll
  for (int r = 0; r < TSCAN; ++r) {
    float4 x = *(const float4*)&base[(size_t)r * Dq];
    s.x += x.x; s.y += x.y; s.z += x.z; s.w += x.w;
  }
  *(float4*)&tsum[((size_t)b * NTILE + tile) * Dq + d4 * 4] = s;
}

__global__ __launch_bounds__(128) void build_context(
    const float* __restrict__ v, const float* __restrict__ tsum,
    const int* __restrict__ repl, const float* __restrict__ attnv,
    ushort_t* __restrict__ ctxh) {
  int blk = blockIdx.x;  // b*NTILE + tile
  int tile = blk & (NTILE - 1);
  int b = blk >> 7;
  int d4 = threadIdx.x;          // float4 column slice
  int h = d4 >> 4;               // (d4*4)>>6
  // exclusive prefix over preceding tile sums (independent L2 loads)
  float4 run = {0.f, 0.f, 0.f, 0.f};
  const float* tb = &tsum[(size_t)b * NTILE * Dq + d4 * 4];
  for (int i = 0; i < tile; ++i) {
    float4 t = *(const float4*)&tb[(size_t)i * Dq];
    run.x += t.x; run.y += t.y; run.z += t.z; run.w += t.w;
  }
  const int* replb = &repl[(size_t)(b * Hq + h) * Lq + tile * TSCAN];
  const float* vb = &v[((size_t)b * Lq + tile * TSCAN) * Dq + d4 * 4];
  ushort_t* cb = &ctxh[((size_t)b * Lq + tile * TSCAN) * Dq + d4 * 4];
  const float* ab = &attnv[(size_t)(b * Hq + h) * Uq * DKq + (d4 & 15) * 4];
#pragma unroll
  for (int r = 0; r < TSCAN; ++r) {
    float4 x = *(const float4*)&vb[(size_t)r * Dq];
    run.x += x.x; run.y += x.y; run.z += x.z; run.w += x.w;
    int u = replb[r];
    float4 val = run;
    if (u >= 0) val = *(const float4*)&ab[(size_t)u * DKq];
    ushort4 o = {bf16_rne(val.x), bf16_rne(val.y), bf16_rne(val.z),
                 bf16_rne(val.w)};
    *(ushort4*)&cb[(size_t)r * Dq] = o;
  }
}

// ---------------------------------------------------------------------------
extern "C" void kernel_launch(void* const* d_in, const int* in_sizes, int n_in,
                              void* d_out, int out_size, void* d_ws,
                              size_t ws_size, hipStream_t stream) {
  const float* queries = (const float*)d_in[0];
  const float* keys    = (const float*)d_in[1];
  const float* values  = (const float*)d_in[2];
  const int*   idxs    = (const int*)d_in[3];
  const float* Wq = (const float*)d_in[4];
  const float* bq = (const float*)d_in[5];
  const float* Wk = (const float*)d_in[6];
  const float* bk = (const float*)d_in[7];
  const float* Wv = (const float*)d_in[8];
  const float* bv = (const float*)d_in[9];
  const float* Wo = (const float*)d_in[10];
  const float* bo = (const float*)d_in[11];
  float* out = (float*)d_out;

  const size_t BLD = (size_t)Bq * Lq * Dq;  // 4,194,304
  char* w = (char*)d_ws;
  float* q    = (float*)w; w += BLD * 4;
  float* k    = (float*)w; w += BLD * 4;
  float* v    = (float*)w; w += BLD * 4;
  float* scg  = (float*)w; w += (size_t)Bq * Hq * Uq * Lq * 4;  // 6.3 MB
  float* m    = (float*)w; w += (size_t)Bq * Hq * Lq * 4;
  float* attnv= (float*)w; w += (size_t)Bq * Hq * Uq * DKq * 4;
  float* tsum = (float*)w; w += (size_t)Bq * NTILE * Dq * 4;
  int* mtop   = (int*)w;   w += Bq * Hq * Uq * 4;
  int* repl   = (int*)w;   w += (size_t)Bq * Hq * Lq * 4;
  float* pmax = (float*)w; w += (size_t)Bq * Hq * Uq * NCH * 4;
  float* psum = (float*)w; w += (size_t)Bq * Hq * Uq * NCH * 4;
  float* pvp  = (float*)w; w += (size_t)Bq * Hq * Uq * NCH * DKq * 4;
  u64* cand   = (u64*)w;   w += (size_t)Bq * Hq * TKCH * Uq * 8;
  ushort_t* ctxh = (ushort_t*)w; w += BLD * 2;  // bf16 context
  ushort_t* Aqh = (ushort_t*)w; w += BLD * 2;   // pre-cast activations
  ushort_t* Aql = (ushort_t*)w; w += BLD * 2;
  ushort_t* Akh = (ushort_t*)w; w += BLD * 2;
  ushort_t* Akl = (ushort_t*)w; w += BLD * 2;
  ushort_t* Avh = (ushort_t*)w; w += BLD * 2;
  const size_t WSZ = 512 * 512;
  ushort_t* Wqh = (ushort_t*)w; w += WSZ * 2;
  ushort_t* Wql = (ushort_t*)w; w += WSZ * 2;
  ushort_t* Wkh = (ushort_t*)w; w += WSZ * 2;
  ushort_t* Wkl = (ushort_t*)w; w += WSZ * 2;
  ushort_t* Wvh = (ushort_t*)w; w += WSZ * 2;
  ushort_t* Woh = (ushort_t*)w; w += WSZ * 2;

  // weights: transpose + hi/lo cast, one launch
  {
    dim3 tgrid(16, 16, 4);
    transpose_cast4<<<tgrid, 256, 0, stream>>>(Wq, Wk, Wv, Wo, Wqh, Wql, Wkh,
                                               Wkl, Wvh, Woh);
  }

  // pre-cast activations, one launch (Q,K hi/lo; V hi)
  {
    dim3 cgrid(BLD / 4 / 256, 3);  // (4096, 3)
    cast_all<<<cgrid, 256, 0, stream>>>(queries, keys, values, Aqh, Aql, Akh,
                                        Akl, Avh);
  }

  // fused Q/K/V projections (128x128 tiles, async LDS staging)
  {
    dim3 ggrid(64, 4, 3);  // M=8192/128, N=512/128, z = Q/K/V
    gemm_qkv<<<ggrid, 256, 0, stream>>>(Aqh, Aql, Akh, Akl, Avh, Wqh, Wql,
                                        Wkh, Wkl, Wvh, bq, bk, bv, q, k, v);
  }

  // sparsity metric + top-k (two-stage bitonic; stage2 also builds repl)
  compute_m<<<(Bq * Hq * Lq) / 16, 256, 0, stream>>>(q, k, idxs, m);
  topk_stage1<<<Bq * Hq * TKCH, 256, 0, stream>>>(m, cand);
  topk_stage2<<<Bq * Hq, 256, 0, stream>>>(cand, mtop, repl);

  // attention on the top-24 rows
  {
    dim3 sgrid(Lq / JT, Bq * Hq);  // (8, 32)
    scores_kernel<<<sgrid, 256, 0, stream>>>(q, k, mtop, scg);
  }
  {
    dim3 pgrid(NCH, Bq * Hq * Uq);  // (8, 768)
    softmax_pv_partial<<<pgrid, 256, 0, stream>>>(scg, v, mtop, pmax, psum, pvp);
    softmax_pv_combine<<<Bq * Hq * Uq / 4, 256, 0, stream>>>(pmax, psum, pvp,
                                                             mtop, attnv);
  }

  // cumsum context + scatter, bf16 output (inline prefix — no tile_prefix)
  tile_sum<<<Bq * NTILE, 128, 0, stream>>>(v, tsum);
  build_context<<<Bq * NTILE, 128, 0, stream>>>(v, tsum, repl, attnv, ctxh);

  // output projection (plain bf16, 128x128 tiles, async LDS staging)
  {
    dim3 ggrid(64, 4);
    gemm_bf16<<<ggrid, 256, 0, stream>>>(ctxh, Woh, bo, out);
  }
}